// Round 16
// baseline (230.979 us; speedup 1.0000x reference)
//
#include <hip/hip_runtime.h>
#include <hip/hip_bf16.h>

// WindowAttention v16: qkv split 3-ways by output (s=0:q, 1:k, 2:v) -> grid 3072,
// 6 chunks + 5 barriers per block, ~2-3x resident blocks/CU for latency overlap.
// attn/proj/prep identical to r14 (184us proven set).
// N=128 tokens, B_=1024 windows, C=192, H=6, hd=32.
// ws: bmF f32 [6*64][16384] ((bias+mask)*LOG2E, r6 frag order) |
//     wbf bf16[576][192] GLOBAL-SWIZZLED (short col ^ (row&7)<<3) | pwbf linear |
//     q bf16 [b][h][128][32] linear, pre-scaled SCALE*LOG2E |
//     k swz (short col ^ ((tok>>1)&3)<<3) | v^T swz (short col ^ (d&15)<<3)
// attn bf16 out in d_out slot: d_out + b*98304 + 49152 (block-private).

typedef float f32x4 __attribute__((ext_vector_type(4)));
typedef short short8 __attribute__((ext_vector_type(8)));
typedef short short4e __attribute__((ext_vector_type(4)));

#define SCALE 0.17677669529663687f
#define LOG2E 1.4426950408889634f
#define QSC (SCALE * LOG2E)

#define GLOAD16(src, dst)                                                      \
  __builtin_amdgcn_global_load_lds(                                            \
      (const __attribute__((address_space(1))) unsigned int*)(const void*)(src),\
      (__attribute__((address_space(3))) unsigned int*)(void*)(dst), 16, 0, 0)

static __device__ __forceinline__ short f2bf(float f) {
  __hip_bfloat16 h = __float2bfloat16(f);
  return __builtin_bit_cast(short, h);
}
static __device__ __forceinline__ f32x4 mfma16(short8 a, short8 b, f32x4 c) {
  return __builtin_amdgcn_mfma_f32_16x16x32_bf16(a, b, c, 0, 0, 0);
}

// ---------------- prep: qkv_w -> bf16 swizzled, proj_w -> bf16 linear ----------------
__global__ __launch_bounds__(256) void prep_w(const float* __restrict__ qkvw,
                                              const float* __restrict__ projw,
                                              short* __restrict__ wbf,
                                              short* __restrict__ pwbf) {
  int t = blockIdx.x * 256 + threadIdx.x;  // float4 index 0..36863
  const int NQ = 27648;                    // 576*192/4
  float4 f; short* dst;
  if (t < NQ) {
    f = ((const float4*)qkvw)[t];
    int row = (t * 4) / 192, c4 = (t * 4) % 192;
    dst = wbf + row * 192 + (c4 ^ ((row & 7) << 3));  // row-local: key<=56<192 shorts
  } else {
    f = ((const float4*)projw)[t - NQ];
    dst = pwbf + (t - NQ) * 4;
  }
  short4e o; o[0] = f2bf(f.x); o[1] = f2bf(f.y); o[2] = f2bf(f.z); o[3] = f2bf(f.w);
  *(short4e*)dst = o;
}

// ---------------- prep_bm: (bias+mask)*LOG2E tiles, r6 fragment layout ----------------
__global__ __launch_bounds__(256) void prep_bm(const int* __restrict__ rel,
                                               const float* __restrict__ table,
                                               const float* __restrict__ mask,
                                               float* __restrict__ bmF) {
  int blk = blockIdx.x;            // 384 blocks: h*64 + w
  int h = blk >> 6, w = blk & 63;
  int tid = threadIdx.x, lane = tid & 63, wave = tid >> 6;
  int lr = lane & 15, r4 = (lane >> 4) * 4;
  const float* mk = mask + (size_t)w * 16384;
  float* dst = bmF + (size_t)blk * 16384;
#pragma unroll
  for (int L = 0; L < 16; ++L) {
    int rf = L >> 3, rg = (L >> 1) & 3, cp = L & 1;
    int row = wave * 32 + rf * 16 + r4 + rg;
    float4 v;
#pragma unroll
    for (int e = 0; e < 4; ++e) {
      int col = (cp * 4 + e) * 16 + lr;
      float bias = table[rel[row * 128 + col] * 6 + h];
      ((float*)&v)[e] = (bias + mk[row * 128 + col]) * LOG2E;
    }
    ((float4*)dst)[L * 256 + tid] = v;
  }
}

// ---------------- qkv: 3-way split by output; x in regs, W via GLOAD dbuf ----------------
__global__ __launch_bounds__(256, 4) void qkv_kernel(const float* __restrict__ x,
                                                     const short* __restrict__ wbf,
                                                     short* __restrict__ qb,
                                                     short* __restrict__ kb,
                                                     short* __restrict__ vb) {
  __shared__ short wt[2][6144];  // [32][192] bf16 dbuf, image already swizzled
  char* wtb = (char*)wt;
  const int bid = blockIdx.x;
  const int b = bid / 3, s = bid - b * 3;   // s: 0=q, 1=k, 2=v
  const int tid = threadIdx.x;
  const int wave = tid >> 6, lane = tid & 63;
  const int lr = lane & 15, g = lane >> 4, g8 = g * 8, r4 = g * 4;
  const int rowbase = wave * 32;
  const int xorkey = (lr & 7) << 4;
  const int wl = wave * 1024 + lane * 16;   // per-lane src byte offset
  const int wu = wave * 1024;               // wave-uniform LDS byte offset
  const int ch0 = s * 6;

  // x -> fragments: rows rowbase+tf*16+lr, kdim g*8..
  short8 xa[2][6];
  {
    const float* xr = x + (size_t)b * 24576 + (size_t)(rowbase + lr) * 192;
#pragma unroll
    for (int tf = 0; tf < 2; ++tf)
#pragma unroll
      for (int ks = 0; ks < 6; ++ks) {
        const float* p = xr + tf * 16 * 192 + ks * 32 + g8;
        float4 f0 = *(const float4*)p;
        float4 f1 = *(const float4*)(p + 4);
        short8 v8;
        v8[0] = f2bf(f0.x); v8[1] = f2bf(f0.y); v8[2] = f2bf(f0.z); v8[3] = f2bf(f0.w);
        v8[4] = f2bf(f1.x); v8[5] = f2bf(f1.y); v8[6] = f2bf(f1.z); v8[7] = f2bf(f1.w);
        xa[tf][ks] = v8;
      }
  }
  // stage first chunk of this split
  {
    const char* wsrc = (const char*)wbf + ch0 * 12288;
#pragma unroll
    for (int i = 0; i < 3; ++i)
      GLOAD16(wsrc + i * 4096 + wl, wtb + i * 4096 + wu);
  }
  __syncthreads();

  short* dstqk = (s == 0) ? qb : kb;
  const float sc = (s == 0) ? QSC : 1.0f;

  for (int cc = 0; cc < 6; ++cc) {
    if (cc < 5) {
      const char* wsrc = (const char*)wbf + (ch0 + cc + 1) * 12288;
      char* wdst = wtb + ((cc + 1) & 1) * 12288;
#pragma unroll
      for (int i = 0; i < 3; ++i)
        GLOAD16(wsrc + i * 4096 + wl, wdst + i * 4096 + wu);
    }
    const char* wb = wtb + (cc & 1) * 12288;
    f32x4 acc[2][2];
    acc[0][0] = acc[0][1] = acc[1][0] = acc[1][1] = f32x4{0.f, 0.f, 0.f, 0.f};
    size_t base = ((size_t)b * 6 + cc) * 4096;  // h == cc for every split
    if (s < 2) {
      // q/k: swapped MFMA, D[wcol][tok]; acc[cf][tf]
      __builtin_amdgcn_s_setprio(1);
#pragma unroll
      for (int ks = 0; ks < 6; ++ks) {
        int cx = (ks * 64 + g * 16) ^ xorkey;
        short8 w0 = *(const short8*)(wb + lr * 384 + cx);
        short8 w1 = *(const short8*)(wb + (16 + lr) * 384 + cx);
        acc[0][0] = mfma16(w0, xa[0][ks], acc[0][0]);
        acc[0][1] = mfma16(w0, xa[1][ks], acc[0][1]);
        acc[1][0] = mfma16(w1, xa[0][ks], acc[1][0]);
        acc[1][1] = mfma16(w1, xa[1][ks], acc[1][1]);
      }
      __builtin_amdgcn_s_setprio(0);
      const bool isq = (s == 0);
#pragma unroll
      for (int cf = 0; cf < 2; ++cf)
#pragma unroll
        for (int tf = 0; tf < 2; ++tf) {
          int tok = rowbase + tf * 16 + lr;
          int col = cf * 16 + r4;
          int idx = isq ? col : (col ^ (((tok >> 1) & 3) << 3));
          short4e s4;
          s4[0] = f2bf(acc[cf][tf][0] * sc);
          s4[1] = f2bf(acc[cf][tf][1] * sc);
          s4[2] = f2bf(acc[cf][tf][2] * sc);
          s4[3] = f2bf(acc[cf][tf][3] * sc);
          *(short4e*)&dstqk[base + (size_t)tok * 32 + idx] = s4;
        }
    } else {
      // v: non-swapped MFMA, D[tok][wcol]; acc[tf][cf] -> v^T swizzled stores
      __builtin_amdgcn_s_setprio(1);
#pragma unroll
      for (int ks = 0; ks < 6; ++ks) {
        int cx = (ks * 64 + g * 16) ^ xorkey;
        short8 w0 = *(const short8*)(wb + lr * 384 + cx);
        short8 w1 = *(const short8*)(wb + (16 + lr) * 384 + cx);
        acc[0][0] = mfma16(xa[0][ks], w0, acc[0][0]);
        acc[0][1] = mfma16(xa[0][ks], w1, acc[0][1]);
        acc[1][0] = mfma16(xa[1][ks], w0, acc[1][0]);
        acc[1][1] = mfma16(xa[1][ks], w1, acc[1][1]);
      }
      __builtin_amdgcn_s_setprio(0);
#pragma unroll
      for (int tf = 0; tf < 2; ++tf)
#pragma unroll
        for (int cf = 0; cf < 2; ++cf) {
          int d = cf * 16 + lr;
          int rowpos = rowbase + tf * 16 + r4;
          short4e s4;
          s4[0] = f2bf(acc[tf][cf][0]);
          s4[1] = f2bf(acc[tf][cf][1]);
          s4[2] = f2bf(acc[tf][cf][2]);
          s4[3] = f2bf(acc[tf][cf][3]);
          *(short4e*)&vb[base + (size_t)d * 128 + (rowpos ^ ((d & 15) << 3))] = s4;
        }
    }
    if (cc < 5) __syncthreads();
  }
}

// ---------------- attn per (window,head): GLOAD k/v, q direct, 32KB LDS, 4 blk/CU ----------------
__global__ __launch_bounds__(256, 4) void attn_kernel(const short* __restrict__ qb,
                                                      const short* __restrict__ kb,
                                                      const short* __restrict__ vb,
                                                      const float* __restrict__ bmF,
                                                      char* __restrict__ outc) {
  __shared__ char sbuf[16384];   // k 8KB | v 8KB (swizzled images)
  __shared__ short p_lds[8192];  // 4 waves x 4KB P scratch
  const int bh = blockIdx.x, b = bh / 6, h = bh - b * 6;
  const short* qt = qb + (size_t)bh * 4096;
  const char* kc = (const char*)(kb + (size_t)bh * 4096);
  const char* vc = (const char*)(vb + (size_t)bh * 4096);
  const float4* bm4 = (const float4*)(bmF + ((size_t)h * 64 + (b & 63)) * 16384);
  short* outSlot = (short*)(outc + (size_t)b * 98304 + 49152);
  const int tid = threadIdx.x, wave = tid >> 6, lane = tid & 63;
  const int lr = lane & 15, g = lane >> 4, r4 = g * 4;
  const int rowbase = wave * 32;
  const int wl = wave * 1024 + lane * 16;
  const int wu = wave * 1024;

  // deep-queue stage: k,v 16KB via 4 global_load_lds per thread
  GLOAD16(kc + wl,        sbuf + wu);
  GLOAD16(kc + 4096 + wl, sbuf + 4096 + wu);
  GLOAD16(vc + wl,        sbuf + 8192 + wu);
  GLOAD16(vc + 4096 + wl, sbuf + 12288 + wu);
  // q: wave-private rows, direct global->reg (coalesced), independent of LDS
  short8 qaH[2];
  qaH[0] = *(const short8*)&qt[(rowbase + lr) * 32 + g * 8];
  qaH[1] = *(const short8*)&qt[(rowbase + 16 + lr) * 32 + g * 8];
  __syncthreads();

  const char* ksb = sbuf;
  const char* vs = sbuf + 8192;
  char* pw = (char*)p_lds + wave * 4096;
  const int kkey = ((lr >> 1) & 3) << 4;  // k-row swizzle key (krow>>1)&3 == (lr>>1)&3

#pragma unroll
  for (int rf = 0; rf < 2; ++rf) {
    // prefetch bias+mask fragments for this rf (8 x 16B)
    float4 bmv[8];
#pragma unroll
    for (int i = 0; i < 8; ++i) bmv[i] = bm4[(rf * 8 + i) * 256 + tid];
    short8 qa = qaH[rf];
    f32x4 s[8];
    __builtin_amdgcn_s_setprio(1);
#pragma unroll
    for (int cf = 0; cf < 8; ++cf) {
      int krow = cf * 16 + lr;
      short8 kf = *(const short8*)(ksb + krow * 64 + ((g * 16) ^ kkey));
      f32x4 z = {0.f, 0.f, 0.f, 0.f};
      s[cf] = mfma16(qa, kf, z);
    }
    __builtin_amdgcn_s_setprio(0);
    float inv_[4];
#pragma unroll
    for (int rg = 0; rg < 4; ++rg) {
      float4 bb0 = bmv[rg * 2];
      float4 bb1 = bmv[rg * 2 + 1];
      float p0 = exp2f(s[0][rg] + bb0.x);
      float p1 = exp2f(s[1][rg] + bb0.y);
      float p2 = exp2f(s[2][rg] + bb0.z);
      float p3 = exp2f(s[3][rg] + bb0.w);
      float p4 = exp2f(s[4][rg] + bb1.x);
      float p5 = exp2f(s[5][rg] + bb1.y);
      float p6 = exp2f(s[6][rg] + bb1.z);
      float p7 = exp2f(s[7][rg] + bb1.w);
      float sum = ((p0 + p1) + (p2 + p3)) + ((p4 + p5) + (p6 + p7));
#pragma unroll
      for (int o = 1; o < 16; o <<= 1) sum += __shfl_xor(sum, o);
      inv_[rg] = 1.0f / sum;
      int rr = r4 + rg;                 // row within this rf's 16
      int base = rr * 256 + (lr << 1);
      int swz = rr << 4;
      *(short*)(pw + ((base + 0 * 32) ^ swz)) = f2bf(p0);
      *(short*)(pw + ((base + 1 * 32) ^ swz)) = f2bf(p1);
      *(short*)(pw + ((base + 2 * 32) ^ swz)) = f2bf(p2);
      *(short*)(pw + ((base + 3 * 32) ^ swz)) = f2bf(p3);
      *(short*)(pw + ((base + 4 * 32) ^ swz)) = f2bf(p4);
      *(short*)(pw + ((base + 5 * 32) ^ swz)) = f2bf(p5);
      *(short*)(pw + ((base + 6 * 32) ^ swz)) = f2bf(p6);
      *(short*)(pw + ((base + 7 * 32) ^ swz)) = f2bf(p7);
    }
    // PV: D[qtok][d]; P (wave-private) + V from LDS, no barrier
    f32x4 o0 = {0.f, 0.f, 0.f, 0.f}, o1 = {0.f, 0.f, 0.f, 0.f};
#pragma unroll
    for (int kst = 0; kst < 4; ++kst) {
      short8 pa = *(const short8*)(pw + ((lr * 256 + kst * 64 + g * 16) ^ (lr << 4)));
      short8 vb0 = *(const short8*)(vs + ((lr * 256 + kst * 64 + g * 16) ^ ((lr & 15) << 4)));
      short8 vb1 = *(const short8*)(vs + (((16 + lr) * 256 + kst * 64 + g * 16) ^ (((16 + lr) & 15) << 4)));
      __builtin_amdgcn_s_setprio(1);
      o0 = mfma16(pa, vb0, o0);
      o1 = mfma16(pa, vb1, o1);
      __builtin_amdgcn_s_setprio(0);
    }
    // epilogue (round-6 proven scalar form)
#pragma unroll
    for (int rg = 0; rg < 4; ++rg) {
      int tok = rowbase + rf * 16 + r4 + rg;
      float iv = inv_[rg];
      outSlot[(size_t)tok * 192 + h * 32 + lr] = f2bf(o0[rg] * iv);
      outSlot[(size_t)tok * 192 + h * 32 + 16 + lr] = f2bf(o1[rg] * iv);
    }
  }
}

// ---------------- proj: ain[128][192] (bf16 in own d_out slot) @ proj_w^T + b ----------------
__global__ __launch_bounds__(256, 2) void proj_kernel(const short* __restrict__ pwbf,
                                                      const float* __restrict__ pb,
                                                      float* __restrict__ out) {
  __shared__ short at[24576];
  __shared__ short wt[2][6144];
  const int b = blockIdx.x, tid = threadIdx.x;
  const int wave = tid >> 6, lane = tid & 63;
  const int lr = lane & 15, g = lane >> 4;
  const int g16 = g * 16, r4 = g * 4;
  const int rowbase = wave * 32;
  const int xorkey = (lr & 7) << 4;
  char* atb = (char*)at;
  char* wtb = (char*)wt;

  int wsoff[3], wdoff[3];
#pragma unroll
  for (int i = 0; i < 3; ++i) {
    int idx8 = i * 256 + tid;
    int r = idx8 / 24, c = idx8 - r * 24;
    wsoff[i] = idx8 * 8;
    wdoff[i] = r * 384 + ((c * 16) ^ ((r & 7) << 4));
  }
  short8 wreg[3];
#pragma unroll
  for (int i = 0; i < 3; ++i) wreg[i] = *(const short8*)(pwbf + wsoff[i]);

  const short8* ar = (const short8*)((const char*)out + (size_t)b * 98304 + 49152);
#pragma unroll
  for (int i = 0; i < 12; ++i) {
    int idx8 = i * 256 + tid;
    int r = idx8 / 24, c = idx8 - r * 24;
    short8 v = ar[idx8];
    *(short8*)(atb + r * 384 + ((c * 16) ^ ((r & 7) << 4))) = v;
  }
#pragma unroll
  for (int i = 0; i < 3; ++i) *(short8*)(wtb + wdoff[i]) = wreg[i];
  __syncthreads();

  const int rA0 = (rowbase + lr) * 384, rA1 = rA0 + 16 * 384;
  const int wB0 = lr * 384, wB1 = wB0 + 16 * 384;

  for (int ch = 0; ch < 6; ++ch) {
    if (ch < 5) {
#pragma unroll
      for (int i = 0; i < 3; ++i)
        wreg[i] = *(const short8*)(pwbf + (ch + 1) * 6144 + wsoff[i]);
    }
    const char* wbuf = wtb + (ch & 1) * 12288;
    f32x4 acc[2][2];
    acc[0][0] = acc[0][1] = acc[1][0] = acc[1][1] = f32x4{0.f, 0.f, 0.f, 0.f};
#pragma unroll
    for (int ks = 0; ks < 6; ++ks) {
      int cx = (ks * 64 + g16) ^ xorkey;
      short8 xa0 = *(const short8*)(atb + rA0 + cx);
      short8 xa1 = *(const short8*)(atb + rA1 + cx);
      short8 wf0 = *(const short8*)(wbuf + wB0 + cx);
      short8 wf1 = *(const short8*)(wbuf + wB1 + cx);
      acc[0][0] = mfma16(xa0, wf0, acc[0][0]);
      acc[0][1] = mfma16(xa0, wf1, acc[0][1]);
      acc[1][0] = mfma16(xa1, wf0, acc[1][0]);
      acc[1][1] = mfma16(xa1, wf1, acc[1][1]);
    }
#pragma unroll
    for (int cf = 0; cf < 2; ++cf) {
      int j = ch * 32 + cf * 16 + lr;
      float bj = pb[j];
#pragma unroll
      for (int rf = 0; rf < 2; ++rf)
#pragma unroll
        for (int rg = 0; rg < 4; ++rg) {
          int tok = rowbase + rf * 16 + r4 + rg;
          out[((size_t)b * 128 + tok) * 192 + j] = acc[rf][cf][rg] + bj;
        }
    }
    if (ch < 5) {
#pragma unroll
      for (int i = 0; i < 3; ++i)
        *(short8*)(wtb + ((ch + 1) & 1) * 12288 + wdoff[i]) = wreg[i];
      __syncthreads();
    }
  }
}

extern "C" void kernel_launch(void* const* d_in, const int* in_sizes, int n_in,
                              void* d_out, int out_size, void* d_ws, size_t ws_size,
                              hipStream_t stream) {
  const float* x      = (const float*)d_in[0];
  const float* mask   = (const float*)d_in[1];
  const float* qkv_w  = (const float*)d_in[2];
  const float* proj_w = (const float*)d_in[3];
  const float* proj_b = (const float*)d_in[4];
  const float* table  = (const float*)d_in[5];
  const int*   rel    = (const int*)d_in[6];
  char* ws = (char*)d_ws;
  size_t o = 0;
  float* bmF  = (float*)(ws + o); o += 25165824;   // 384 * 16384 * 4
  short* wbf  = (short*)(ws + o); o += 221184;
  short* pwbf = (short*)(ws + o); o += 73728;
  short* qbp  = (short*)(ws + o); o += 50331648;
  short* kbp  = (short*)(ws + o); o += 50331648;
  short* vbp  = (short*)(ws + o); o += 50331648;
  float* out = (float*)d_out;

  prep_w<<<144, 256, 0, stream>>>(qkv_w, proj_w, wbf, pwbf);
  prep_bm<<<384, 256, 0, stream>>>(rel, table, mask, bmF);
  qkv_kernel<<<3072, 256, 0, stream>>>(x, wbf, qbp, kbp, vbp);
  attn_kernel<<<6144, 256, 0, stream>>>(qbp, kbp, vbp, bmF, (char*)d_out);
  proj_kernel<<<1024, 256, 0, stream>>>(pwbf, proj_b, (float*)d_out);
}

// Round 17
// 175.594 us; speedup vs baseline: 1.3154x; 1.3154x over previous
//
#include <hip/hip_runtime.h>
#include <hip/hip_bf16.h>

// WindowAttention v17: qkv processes 2 WINDOWS per block (grid 512) — same 24KB
// W dbuf feeds 48 MFMA/chunk, halving per-window barrier+W-fetch cost. VGPR ~150,
// lb(256,2) -> 2 blocks/CU. attn/proj/prep identical to r14/r15 (182-184us proven).
// N=128 tokens, B_=1024 windows, C=192, H=6, hd=32.
// ws: bmF f32 [6*64][16384] ((bias+mask)*LOG2E, r6 frag order) |
//     wbf bf16[576][192] GLOBAL-SWIZZLED (short col ^ (row&7)<<3) | pwbf linear |
//     q bf16 [b][h][128][32] linear, pre-scaled SCALE*LOG2E |
//     k swz (short col ^ ((tok>>1)&3)<<3) | v^T swz (short col ^ (d&15)<<3)
// attn bf16 out in d_out slot: d_out + b*98304 + 49152 (block-private).

typedef float f32x4 __attribute__((ext_vector_type(4)));
typedef short short8 __attribute__((ext_vector_type(8)));
typedef short short4e __attribute__((ext_vector_type(4)));

#define SCALE 0.17677669529663687f
#define LOG2E 1.4426950408889634f
#define QSC (SCALE * LOG2E)

#define GLOAD16(src, dst)                                                      \
  __builtin_amdgcn_global_load_lds(                                            \
      (const __attribute__((address_space(1))) unsigned int*)(const void*)(src),\
      (__attribute__((address_space(3))) unsigned int*)(void*)(dst), 16, 0, 0)

static __device__ __forceinline__ short f2bf(float f) {
  __hip_bfloat16 h = __float2bfloat16(f);
  return __builtin_bit_cast(short, h);
}
static __device__ __forceinline__ f32x4 mfma16(short8 a, short8 b, f32x4 c) {
  return __builtin_amdgcn_mfma_f32_16x16x32_bf16(a, b, c, 0, 0, 0);
}

// ---------------- prep: qkv_w -> bf16 swizzled, proj_w -> bf16 linear ----------------
__global__ __launch_bounds__(256) void prep_w(const float* __restrict__ qkvw,
                                              const float* __restrict__ projw,
                                              short* __restrict__ wbf,
                                              short* __restrict__ pwbf) {
  int t = blockIdx.x * 256 + threadIdx.x;  // float4 index 0..36863
  const int NQ = 27648;                    // 576*192/4
  float4 f; short* dst;
  if (t < NQ) {
    f = ((const float4*)qkvw)[t];
    int row = (t * 4) / 192, c4 = (t * 4) % 192;
    dst = wbf + row * 192 + (c4 ^ ((row & 7) << 3));  // row-local: key<=56<192 shorts
  } else {
    f = ((const float4*)projw)[t - NQ];
    dst = pwbf + (t - NQ) * 4;
  }
  short4e o; o[0] = f2bf(f.x); o[1] = f2bf(f.y); o[2] = f2bf(f.z); o[3] = f2bf(f.w);
  *(short4e*)dst = o;
}

// ---------------- prep_bm: (bias+mask)*LOG2E tiles, r6 fragment layout ----------------
__global__ __launch_bounds__(256) void prep_bm(const int* __restrict__ rel,
                                               const float* __restrict__ table,
                                               const float* __restrict__ mask,
                                               float* __restrict__ bmF) {
  int blk = blockIdx.x;            // 384 blocks: h*64 + w
  int h = blk >> 6, w = blk & 63;
  int tid = threadIdx.x, lane = tid & 63, wave = tid >> 6;
  int lr = lane & 15, r4 = (lane >> 4) * 4;
  const float* mk = mask + (size_t)w * 16384;
  float* dst = bmF + (size_t)blk * 16384;
#pragma unroll
  for (int L = 0; L < 16; ++L) {
    int rf = L >> 3, rg = (L >> 1) & 3, cp = L & 1;
    int row = wave * 32 + rf * 16 + r4 + rg;
    float4 v;
#pragma unroll
    for (int e = 0; e < 4; ++e) {
      int col = (cp * 4 + e) * 16 + lr;
      float bias = table[rel[row * 128 + col] * 6 + h];
      ((float*)&v)[e] = (bias + mk[row * 128 + col]) * LOG2E;
    }
    ((float4*)dst)[L * 256 + tid] = v;
  }
}

// ---------------- qkv: 2 windows/block, x in regs, W via GLOAD dbuf ----------------
__global__ __launch_bounds__(256, 2) void qkv_kernel(const float* __restrict__ x,
                                                     const short* __restrict__ wbf,
                                                     short* __restrict__ qb,
                                                     short* __restrict__ kb,
                                                     short* __restrict__ vb) {
  __shared__ short wt[2][6144];  // [32][192] bf16 dbuf, image already swizzled
  char* wtb = (char*)wt;
  const int bid = blockIdx.x;
  const int b0 = bid * 2, b1 = bid * 2 + 1;
  const int tid = threadIdx.x;
  const int wave = tid >> 6, lane = tid & 63;
  const int lr = lane & 15, g = lane >> 4, g8 = g * 8, r4 = g * 4;
  const int rowbase = wave * 32;
  const int xorkey = (lr & 7) << 4;
  const int wl = wave * 1024 + lane * 16;   // per-lane src byte offset
  const int wu = wave * 1024;               // wave-uniform LDS byte offset

  // x -> fragments for BOTH windows: rows rowbase+tf*16+lr, kdim g*8..
  short8 xa0[2][6], xa1[2][6];
  {
    const float* xr0 = x + (size_t)b0 * 24576 + (size_t)(rowbase + lr) * 192;
    const float* xr1 = x + (size_t)b1 * 24576 + (size_t)(rowbase + lr) * 192;
#pragma unroll
    for (int tf = 0; tf < 2; ++tf)
#pragma unroll
      for (int ks = 0; ks < 6; ++ks) {
        const float* p0 = xr0 + tf * 16 * 192 + ks * 32 + g8;
        const float* p1 = xr1 + tf * 16 * 192 + ks * 32 + g8;
        float4 a0 = *(const float4*)p0;
        float4 a1 = *(const float4*)(p0 + 4);
        float4 c0 = *(const float4*)p1;
        float4 c1 = *(const float4*)(p1 + 4);
        short8 v8;
        v8[0] = f2bf(a0.x); v8[1] = f2bf(a0.y); v8[2] = f2bf(a0.z); v8[3] = f2bf(a0.w);
        v8[4] = f2bf(a1.x); v8[5] = f2bf(a1.y); v8[6] = f2bf(a1.z); v8[7] = f2bf(a1.w);
        xa0[tf][ks] = v8;
        short8 w8;
        w8[0] = f2bf(c0.x); w8[1] = f2bf(c0.y); w8[2] = f2bf(c0.z); w8[3] = f2bf(c0.w);
        w8[4] = f2bf(c1.x); w8[5] = f2bf(c1.y); w8[6] = f2bf(c1.z); w8[7] = f2bf(c1.w);
        xa1[tf][ks] = w8;
      }
  }
  // stage chunk 0
  {
    const char* wsrc = (const char*)wbf;
#pragma unroll
    for (int i = 0; i < 3; ++i)
      GLOAD16(wsrc + i * 4096 + wl, wtb + i * 4096 + wu);
  }
  __syncthreads();

  for (int ch = 0; ch < 18; ++ch) {
    if (ch < 17) {
      const char* wsrc = (const char*)wbf + (ch + 1) * 12288;
      char* wdst = wtb + ((ch + 1) & 1) * 12288;
#pragma unroll
      for (int i = 0; i < 3; ++i)
        GLOAD16(wsrc + i * 4096 + wl, wdst + i * 4096 + wu);
    }
    const char* wb = wtb + (ch & 1) * 12288;
    f32x4 acc0[2][2], acc1[2][2];
    acc0[0][0] = acc0[0][1] = acc0[1][0] = acc0[1][1] = f32x4{0.f, 0.f, 0.f, 0.f};
    acc1[0][0] = acc1[0][1] = acc1[1][0] = acc1[1][1] = f32x4{0.f, 0.f, 0.f, 0.f};
    if (ch < 12) {
      // q/k: swapped MFMA, D[wcol][tok]; acc[cf][tf]
      __builtin_amdgcn_s_setprio(1);
#pragma unroll
      for (int ks = 0; ks < 6; ++ks) {
        int cx = (ks * 64 + g * 16) ^ xorkey;
        short8 w0 = *(const short8*)(wb + lr * 384 + cx);
        short8 w1 = *(const short8*)(wb + (16 + lr) * 384 + cx);
        acc0[0][0] = mfma16(w0, xa0[0][ks], acc0[0][0]);
        acc0[0][1] = mfma16(w0, xa0[1][ks], acc0[0][1]);
        acc0[1][0] = mfma16(w1, xa0[0][ks], acc0[1][0]);
        acc0[1][1] = mfma16(w1, xa0[1][ks], acc0[1][1]);
        acc1[0][0] = mfma16(w0, xa1[0][ks], acc1[0][0]);
        acc1[0][1] = mfma16(w0, xa1[1][ks], acc1[0][1]);
        acc1[1][0] = mfma16(w1, xa1[0][ks], acc1[1][0]);
        acc1[1][1] = mfma16(w1, xa1[1][ks], acc1[1][1]);
      }
      __builtin_amdgcn_s_setprio(0);
      const bool isq = (ch < 6);
      short* dst = isq ? qb : kb;
      const int h = isq ? ch : ch - 6;
      const float sc = isq ? QSC : 1.0f;
      size_t base0 = ((size_t)b0 * 6 + h) * 4096;
      size_t base1 = ((size_t)b1 * 6 + h) * 4096;
#pragma unroll
      for (int cf = 0; cf < 2; ++cf)
#pragma unroll
        for (int tf = 0; tf < 2; ++tf) {
          int tok = rowbase + tf * 16 + lr;
          int col = cf * 16 + r4;
          int idx = isq ? col : (col ^ (((tok >> 1) & 3) << 3));
          short4e s0, s1;
          s0[0] = f2bf(acc0[cf][tf][0] * sc);
          s0[1] = f2bf(acc0[cf][tf][1] * sc);
          s0[2] = f2bf(acc0[cf][tf][2] * sc);
          s0[3] = f2bf(acc0[cf][tf][3] * sc);
          s1[0] = f2bf(acc1[cf][tf][0] * sc);
          s1[1] = f2bf(acc1[cf][tf][1] * sc);
          s1[2] = f2bf(acc1[cf][tf][2] * sc);
          s1[3] = f2bf(acc1[cf][tf][3] * sc);
          *(short4e*)&dst[base0 + (size_t)tok * 32 + idx] = s0;
          *(short4e*)&dst[base1 + (size_t)tok * 32 + idx] = s1;
        }
    } else {
      // v: non-swapped MFMA, D[tok][wcol]; acc[tf][cf] -> v^T swizzled stores
      __builtin_amdgcn_s_setprio(1);
#pragma unroll
      for (int ks = 0; ks < 6; ++ks) {
        int cx = (ks * 64 + g * 16) ^ xorkey;
        short8 w0 = *(const short8*)(wb + lr * 384 + cx);
        short8 w1 = *(const short8*)(wb + (16 + lr) * 384 + cx);
        acc0[0][0] = mfma16(xa0[0][ks], w0, acc0[0][0]);
        acc0[0][1] = mfma16(xa0[0][ks], w1, acc0[0][1]);
        acc0[1][0] = mfma16(xa0[1][ks], w0, acc0[1][0]);
        acc0[1][1] = mfma16(xa0[1][ks], w1, acc0[1][1]);
        acc1[0][0] = mfma16(xa1[0][ks], w0, acc1[0][0]);
        acc1[0][1] = mfma16(xa1[0][ks], w1, acc1[0][1]);
        acc1[1][0] = mfma16(xa1[1][ks], w0, acc1[1][0]);
        acc1[1][1] = mfma16(xa1[1][ks], w1, acc1[1][1]);
      }
      __builtin_amdgcn_s_setprio(0);
      const int h = ch - 12;
      size_t base0 = ((size_t)b0 * 6 + h) * 4096;
      size_t base1 = ((size_t)b1 * 6 + h) * 4096;
#pragma unroll
      for (int tf = 0; tf < 2; ++tf)
#pragma unroll
        for (int cf = 0; cf < 2; ++cf) {
          int d = cf * 16 + lr;
          int rowpos = rowbase + tf * 16 + r4;
          int idx = rowpos ^ ((d & 15) << 3);
          short4e s0, s1;
          s0[0] = f2bf(acc0[tf][cf][0]);
          s0[1] = f2bf(acc0[tf][cf][1]);
          s0[2] = f2bf(acc0[tf][cf][2]);
          s0[3] = f2bf(acc0[tf][cf][3]);
          s1[0] = f2bf(acc1[tf][cf][0]);
          s1[1] = f2bf(acc1[tf][cf][1]);
          s1[2] = f2bf(acc1[tf][cf][2]);
          s1[3] = f2bf(acc1[tf][cf][3]);
          *(short4e*)&vb[base0 + (size_t)d * 128 + idx] = s0;
          *(short4e*)&vb[base1 + (size_t)d * 128 + idx] = s1;
        }
    }
    if (ch < 17) __syncthreads();
  }
}

// ---------------- attn per (window,head): GLOAD k/v, q direct, 32KB LDS, 4 blk/CU ----------------
__global__ __launch_bounds__(256, 4) void attn_kernel(const short* __restrict__ qb,
                                                      const short* __restrict__ kb,
                                                      const short* __restrict__ vb,
                                                      const float* __restrict__ bmF,
                                                      char* __restrict__ outc) {
  __shared__ char sbuf[16384];   // k 8KB | v 8KB (swizzled images)
  __shared__ short p_lds[8192];  // 4 waves x 4KB P scratch
  const int bh = blockIdx.x, b = bh / 6, h = bh - b * 6;
  const short* qt = qb + (size_t)bh * 4096;
  const char* kc = (const char*)(kb + (size_t)bh * 4096);
  const char* vc = (const char*)(vb + (size_t)bh * 4096);
  const float4* bm4 = (const float4*)(bmF + ((size_t)h * 64 + (b & 63)) * 16384);
  short* outSlot = (short*)(outc + (size_t)b * 98304 + 49152);
  const int tid = threadIdx.x, wave = tid >> 6, lane = tid & 63;
  const int lr = lane & 15, g = lane >> 4, r4 = g * 4;
  const int rowbase = wave * 32;
  const int wl = wave * 1024 + lane * 16;
  const int wu = wave * 1024;

  // deep-queue stage: k,v 16KB via 4 global_load_lds per thread
  GLOAD16(kc + wl,        sbuf + wu);
  GLOAD16(kc + 4096 + wl, sbuf + 4096 + wu);
  GLOAD16(vc + wl,        sbuf + 8192 + wu);
  GLOAD16(vc + 4096 + wl, sbuf + 12288 + wu);
  // q: wave-private rows, direct global->reg (coalesced), independent of LDS
  short8 qaH[2];
  qaH[0] = *(const short8*)&qt[(rowbase + lr) * 32 + g * 8];
  qaH[1] = *(const short8*)&qt[(rowbase + 16 + lr) * 32 + g * 8];
  __syncthreads();

  const char* ksb = sbuf;
  const char* vs = sbuf + 8192;
  char* pw = (char*)p_lds + wave * 4096;
  const int kkey = ((lr >> 1) & 3) << 4;  // k-row swizzle key (krow>>1)&3 == (lr>>1)&3

#pragma unroll
  for (int rf = 0; rf < 2; ++rf) {
    // prefetch bias+mask fragments for this rf (8 x 16B)
    float4 bmv[8];
#pragma unroll
    for (int i = 0; i < 8; ++i) bmv[i] = bm4[(rf * 8 + i) * 256 + tid];
    short8 qa = qaH[rf];
    f32x4 s[8];
    __builtin_amdgcn_s_setprio(1);
#pragma unroll
    for (int cf = 0; cf < 8; ++cf) {
      int krow = cf * 16 + lr;
      short8 kf = *(const short8*)(ksb + krow * 64 + ((g * 16) ^ kkey));
      f32x4 z = {0.f, 0.f, 0.f, 0.f};
      s[cf] = mfma16(qa, kf, z);
    }
    __builtin_amdgcn_s_setprio(0);
    float inv_[4];
#pragma unroll
    for (int rg = 0; rg < 4; ++rg) {
      float4 bb0 = bmv[rg * 2];
      float4 bb1 = bmv[rg * 2 + 1];
      float p0 = exp2f(s[0][rg] + bb0.x);
      float p1 = exp2f(s[1][rg] + bb0.y);
      float p2 = exp2f(s[2][rg] + bb0.z);
      float p3 = exp2f(s[3][rg] + bb0.w);
      float p4 = exp2f(s[4][rg] + bb1.x);
      float p5 = exp2f(s[5][rg] + bb1.y);
      float p6 = exp2f(s[6][rg] + bb1.z);
      float p7 = exp2f(s[7][rg] + bb1.w);
      float sum = ((p0 + p1) + (p2 + p3)) + ((p4 + p5) + (p6 + p7));
#pragma unroll
      for (int o = 1; o < 16; o <<= 1) sum += __shfl_xor(sum, o);
      inv_[rg] = 1.0f / sum;
      int rr = r4 + rg;                 // row within this rf's 16
      int base = rr * 256 + (lr << 1);
      int swz = rr << 4;
      *(short*)(pw + ((base + 0 * 32) ^ swz)) = f2bf(p0);
      *(short*)(pw + ((base + 1 * 32) ^ swz)) = f2bf(p1);
      *(short*)(pw + ((base + 2 * 32) ^ swz)) = f2bf(p2);
      *(short*)(pw + ((base + 3 * 32) ^ swz)) = f2bf(p3);
      *(short*)(pw + ((base + 4 * 32) ^ swz)) = f2bf(p4);
      *(short*)(pw + ((base + 5 * 32) ^ swz)) = f2bf(p5);
      *(short*)(pw + ((base + 6 * 32) ^ swz)) = f2bf(p6);
      *(short*)(pw + ((base + 7 * 32) ^ swz)) = f2bf(p7);
    }
    // PV: D[qtok][d]; P (wave-private) + V from LDS, no barrier
    f32x4 o0 = {0.f, 0.f, 0.f, 0.f}, o1 = {0.f, 0.f, 0.f, 0.f};
#pragma unroll
    for (int kst = 0; kst < 4; ++kst) {
      short8 pa = *(const short8*)(pw + ((lr * 256 + kst * 64 + g * 16) ^ (lr << 4)));
      short8 vb0 = *(const short8*)(vs + ((lr * 256 + kst * 64 + g * 16) ^ ((lr & 15) << 4)));
      short8 vb1 = *(const short8*)(vs + (((16 + lr) * 256 + kst * 64 + g * 16) ^ (((16 + lr) & 15) << 4)));
      __builtin_amdgcn_s_setprio(1);
      o0 = mfma16(pa, vb0, o0);
      o1 = mfma16(pa, vb1, o1);
      __builtin_amdgcn_s_setprio(0);
    }
    // epilogue (round-6 proven scalar form)
#pragma unroll
    for (int rg = 0; rg < 4; ++rg) {
      int tok = rowbase + rf * 16 + r4 + rg;
      float iv = inv_[rg];
      outSlot[(size_t)tok * 192 + h * 32 + lr] = f2bf(o0[rg] * iv);
      outSlot[(size_t)tok * 192 + h * 32 + 16 + lr] = f2bf(o1[rg] * iv);
    }
  }
}

// ---------------- proj: ain[128][192] (bf16 in own d_out slot) @ proj_w^T + b ----------------
__global__ __launch_bounds__(256, 2) void proj_kernel(const short* __restrict__ pwbf,
                                                      const float* __restrict__ pb,
                                                      float* __restrict__ out) {
  __shared__ short at[24576];
  __shared__ short wt[2][6144];
  const int b = blockIdx.x, tid = threadIdx.x;
  const int wave = tid >> 6, lane = tid & 63;
  const int lr = lane & 15, g = lane >> 4;
  const int g16 = g * 16, r4 = g * 4;
  const int rowbase = wave * 32;
  const int xorkey = (lr & 7) << 4;
  char* atb = (char*)at;
  char* wtb = (char*)wt;

  int wsoff[3], wdoff[3];
#pragma unroll
  for (int i = 0; i < 3; ++i) {
    int idx8 = i * 256 + tid;
    int r = idx8 / 24, c = idx8 - r * 24;
    wsoff[i] = idx8 * 8;
    wdoff[i] = r * 384 + ((c * 16) ^ ((r & 7) << 4));
  }
  short8 wreg[3];
#pragma unroll
  for (int i = 0; i < 3; ++i) wreg[i] = *(const short8*)(pwbf + wsoff[i]);

  const short8* ar = (const short8*)((const char*)out + (size_t)b * 98304 + 49152);
#pragma unroll
  for (int i = 0; i < 12; ++i) {
    int idx8 = i * 256 + tid;
    int r = idx8 / 24, c = idx8 - r * 24;
    short8 v = ar[idx8];
    *(short8*)(atb + r * 384 + ((c * 16) ^ ((r & 7) << 4))) = v;
  }
#pragma unroll
  for (int i = 0; i < 3; ++i) *(short8*)(wtb + wdoff[i]) = wreg[i];
  __syncthreads();

  const int rA0 = (rowbase + lr) * 384, rA1 = rA0 + 16 * 384;
  const int wB0 = lr * 384, wB1 = wB0 + 16 * 384;

  for (int ch = 0; ch < 6; ++ch) {
    if (ch < 5) {
#pragma unroll
      for (int i = 0; i < 3; ++i)
        wreg[i] = *(const short8*)(pwbf + (ch + 1) * 6144 + wsoff[i]);
    }
    const char* wbuf = wtb + (ch & 1) * 12288;
    f32x4 acc[2][2];
    acc[0][0] = acc[0][1] = acc[1][0] = acc[1][1] = f32x4{0.f, 0.f, 0.f, 0.f};
#pragma unroll
    for (int ks = 0; ks < 6; ++ks) {
      int cx = (ks * 64 + g16) ^ xorkey;
      short8 xa0 = *(const short8*)(atb + rA0 + cx);
      short8 xa1 = *(const short8*)(atb + rA1 + cx);
      short8 wf0 = *(const short8*)(wbuf + wB0 + cx);
      short8 wf1 = *(const short8*)(wbuf + wB1 + cx);
      acc[0][0] = mfma16(xa0, wf0, acc[0][0]);
      acc[0][1] = mfma16(xa0, wf1, acc[0][1]);
      acc[1][0] = mfma16(xa1, wf0, acc[1][0]);
      acc[1][1] = mfma16(xa1, wf1, acc[1][1]);
    }
#pragma unroll
    for (int cf = 0; cf < 2; ++cf) {
      int j = ch * 32 + cf * 16 + lr;
      float bj = pb[j];
#pragma unroll
      for (int rf = 0; rf < 2; ++rf)
#pragma unroll
        for (int rg = 0; rg < 4; ++rg) {
          int tok = rowbase + rf * 16 + r4 + rg;
          out[((size_t)b * 128 + tok) * 192 + j] = acc[rf][cf][rg] + bj;
        }
    }
    if (ch < 5) {
#pragma unroll
      for (int i = 0; i < 3; ++i)
        *(short8*)(wtb + ((ch + 1) & 1) * 12288 + wdoff[i]) = wreg[i];
      __syncthreads();
    }
  }
}

extern "C" void kernel_launch(void* const* d_in, const int* in_sizes, int n_in,
                              void* d_out, int out_size, void* d_ws, size_t ws_size,
                              hipStream_t stream) {
  const float* x      = (const float*)d_in[0];
  const float* mask   = (const float*)d_in[1];
  const float* qkv_w  = (const float*)d_in[2];
  const float* proj_w = (const float*)d_in[3];
  const float* proj_b = (const float*)d_in[4];
  const float* table  = (const float*)d_in[5];
  const int*   rel    = (const int*)d_in[6];
  char* ws = (char*)d_ws;
  size_t o = 0;
  float* bmF  = (float*)(ws + o); o += 25165824;   // 384 * 16384 * 4
  short* wbf  = (short*)(ws + o); o += 221184;
  short* pwbf = (short*)(ws + o); o += 73728;
  short* qbp  = (short*)(ws + o); o += 50331648;
  short* kbp  = (short*)(ws + o); o += 50331648;
  short* vbp  = (short*)(ws + o); o += 50331648;
  float* out = (float*)d_out;

  prep_w<<<144, 256, 0, stream>>>(qkv_w, proj_w, wbf, pwbf);
  prep_bm<<<384, 256, 0, stream>>>(rel, table, mask, bmF);
  qkv_kernel<<<512, 256, 0, stream>>>(x, wbf, qbp, kbp, vbp);
  attn_kernel<<<6144, 256, 0, stream>>>(qbp, kbp, vbp, bmF, (char*)d_out);
  proj_kernel<<<1024, 256, 0, stream>>>(pwbf, proj_b, (float*)d_out);
}

// Round 18
// 171.369 us; speedup vs baseline: 1.3478x; 1.0247x over previous
//
#include <hip/hip_runtime.h>
#include <hip/hip_bf16.h>

// WindowAttention v18: r17 (175.6us proven) + merged prep kernel + counted
// vmcnt(8) barriers in the 2-window qkv (drain 3 GLOADs, leave 8 stores in flight).
// N=128 tokens, B_=1024 windows, C=192, H=6, hd=32.
// ws: bmF f32 [6*64][16384] ((bias+mask)*LOG2E, r6 frag order) |
//     wbf bf16[576][192] GLOBAL-SWIZZLED (short col ^ (row&7)<<3) | pwbf linear |
//     q bf16 [b][h][128][32] linear, pre-scaled SCALE*LOG2E |
//     k swz (short col ^ ((tok>>1)&3)<<3) | v^T swz (short col ^ (d&15)<<3)
// attn bf16 out in d_out slot: d_out + b*98304 + 49152 (block-private).

typedef float f32x4 __attribute__((ext_vector_type(4)));
typedef short short8 __attribute__((ext_vector_type(8)));
typedef short short4e __attribute__((ext_vector_type(4)));

#define SCALE 0.17677669529663687f
#define LOG2E 1.4426950408889634f
#define QSC (SCALE * LOG2E)

#define GLOAD16(src, dst)                                                      \
  __builtin_amdgcn_global_load_lds(                                            \
      (const __attribute__((address_space(1))) unsigned int*)(const void*)(src),\
      (__attribute__((address_space(3))) unsigned int*)(void*)(dst), 16, 0, 0)

static __device__ __forceinline__ short f2bf(float f) {
  __hip_bfloat16 h = __float2bfloat16(f);
  return __builtin_bit_cast(short, h);
}
static __device__ __forceinline__ f32x4 mfma16(short8 a, short8 b, f32x4 c) {
  return __builtin_amdgcn_mfma_f32_16x16x32_bf16(a, b, c, 0, 0, 0);
}

// ---------------- prep (merged): W conversion + bm tiles ----------------
__global__ __launch_bounds__(256) void prep_kernel(const float* __restrict__ qkvw,
                                                   const float* __restrict__ projw,
                                                   const int* __restrict__ rel,
                                                   const float* __restrict__ table,
                                                   const float* __restrict__ mask,
                                                   short* __restrict__ wbf,
                                                   short* __restrict__ pwbf,
                                                   float* __restrict__ bmF) {
  int blk = blockIdx.x;
  if (blk < 144) {
    int t = blk * 256 + threadIdx.x;  // float4 index 0..36863
    const int NQ = 27648;             // 576*192/4
    float4 f; short* dst;
    if (t < NQ) {
      f = ((const float4*)qkvw)[t];
      int row = (t * 4) / 192, c4 = (t * 4) % 192;
      dst = wbf + row * 192 + (c4 ^ ((row & 7) << 3));  // row-local swizzle
    } else {
      f = ((const float4*)projw)[t - NQ];
      dst = pwbf + (t - NQ) * 4;
    }
    short4e o; o[0] = f2bf(f.x); o[1] = f2bf(f.y); o[2] = f2bf(f.z); o[3] = f2bf(f.w);
    *(short4e*)dst = o;
  } else {
    int bb = blk - 144;                 // 384 blocks: h*64 + w
    int h = bb >> 6, w = bb & 63;
    int tid = threadIdx.x, lane = tid & 63, wave = tid >> 6;
    int lr = lane & 15, r4 = (lane >> 4) * 4;
    const float* mk = mask + (size_t)w * 16384;
    float* dst = bmF + (size_t)bb * 16384;
#pragma unroll
    for (int L = 0; L < 16; ++L) {
      int rf = L >> 3, rg = (L >> 1) & 3, cp = L & 1;
      int row = wave * 32 + rf * 16 + r4 + rg;
      float4 v;
#pragma unroll
      for (int e = 0; e < 4; ++e) {
        int col = (cp * 4 + e) * 16 + lr;
        float bias = table[rel[row * 128 + col] * 6 + h];
        ((float*)&v)[e] = (bias + mk[row * 128 + col]) * LOG2E;
      }
      ((float4*)dst)[L * 256 + tid] = v;
    }
  }
}

// ---------------- qkv: 2 windows/block, counted-vmcnt(8) barriers ----------------
__global__ __launch_bounds__(256, 2) void qkv_kernel(const float* __restrict__ x,
                                                     const short* __restrict__ wbf,
                                                     short* __restrict__ qb,
                                                     short* __restrict__ kb,
                                                     short* __restrict__ vb) {
  __shared__ short wt[2][6144];  // [32][192] bf16 dbuf, image already swizzled
  char* wtb = (char*)wt;
  const int bid = blockIdx.x;
  const int b0 = bid * 2, b1 = bid * 2 + 1;
  const int tid = threadIdx.x;
  const int wave = tid >> 6, lane = tid & 63;
  const int lr = lane & 15, g = lane >> 4, g8 = g * 8, r4 = g * 4;
  const int rowbase = wave * 32;
  const int xorkey = (lr & 7) << 4;
  const int wl = wave * 1024 + lane * 16;   // per-lane src byte offset
  const int wu = wave * 1024;               // wave-uniform LDS byte offset

  // x -> fragments for BOTH windows
  short8 xa0[2][6], xa1[2][6];
  {
    const float* xr0 = x + (size_t)b0 * 24576 + (size_t)(rowbase + lr) * 192;
    const float* xr1 = x + (size_t)b1 * 24576 + (size_t)(rowbase + lr) * 192;
#pragma unroll
    for (int tf = 0; tf < 2; ++tf)
#pragma unroll
      for (int ks = 0; ks < 6; ++ks) {
        const float* p0 = xr0 + tf * 16 * 192 + ks * 32 + g8;
        const float* p1 = xr1 + tf * 16 * 192 + ks * 32 + g8;
        float4 a0 = *(const float4*)p0;
        float4 a1 = *(const float4*)(p0 + 4);
        float4 c0 = *(const float4*)p1;
        float4 c1 = *(const float4*)(p1 + 4);
        short8 v8;
        v8[0] = f2bf(a0.x); v8[1] = f2bf(a0.y); v8[2] = f2bf(a0.z); v8[3] = f2bf(a0.w);
        v8[4] = f2bf(a1.x); v8[5] = f2bf(a1.y); v8[6] = f2bf(a1.z); v8[7] = f2bf(a1.w);
        xa0[tf][ks] = v8;
        short8 w8;
        w8[0] = f2bf(c0.x); w8[1] = f2bf(c0.y); w8[2] = f2bf(c0.z); w8[3] = f2bf(c0.w);
        w8[4] = f2bf(c1.x); w8[5] = f2bf(c1.y); w8[6] = f2bf(c1.z); w8[7] = f2bf(c1.w);
        xa1[tf][ks] = w8;
      }
  }
  // stage chunk 0
  {
    const char* wsrc = (const char*)wbf;
#pragma unroll
    for (int i = 0; i < 3; ++i)
      GLOAD16(wsrc + i * 4096 + wl, wtb + i * 4096 + wu);
  }
  __syncthreads();

  for (int ch = 0; ch < 18; ++ch) {
    if (ch < 17) {
      const char* wsrc = (const char*)wbf + (ch + 1) * 12288;
      char* wdst = wtb + ((ch + 1) & 1) * 12288;
#pragma unroll
      for (int i = 0; i < 3; ++i)
        GLOAD16(wsrc + i * 4096 + wl, wdst + i * 4096 + wu);
    }
    __builtin_amdgcn_sched_barrier(0);  // pin GLOAD issue before compute/stores
    const char* wb = wtb + (ch & 1) * 12288;
    f32x4 acc0[2][2], acc1[2][2];
    acc0[0][0] = acc0[0][1] = acc0[1][0] = acc0[1][1] = f32x4{0.f, 0.f, 0.f, 0.f};
    acc1[0][0] = acc1[0][1] = acc1[1][0] = acc1[1][1] = f32x4{0.f, 0.f, 0.f, 0.f};
    if (ch < 12) {
      // q/k: swapped MFMA, D[wcol][tok]; acc[cf][tf]
      __builtin_amdgcn_s_setprio(1);
#pragma unroll
      for (int ks = 0; ks < 6; ++ks) {
        int cx = (ks * 64 + g * 16) ^ xorkey;
        short8 w0 = *(const short8*)(wb + lr * 384 + cx);
        short8 w1 = *(const short8*)(wb + (16 + lr) * 384 + cx);
        acc0[0][0] = mfma16(w0, xa0[0][ks], acc0[0][0]);
        acc0[0][1] = mfma16(w0, xa0[1][ks], acc0[0][1]);
        acc0[1][0] = mfma16(w1, xa0[0][ks], acc0[1][0]);
        acc0[1][1] = mfma16(w1, xa0[1][ks], acc0[1][1]);
        acc1[0][0] = mfma16(w0, xa1[0][ks], acc1[0][0]);
        acc1[0][1] = mfma16(w0, xa1[1][ks], acc1[0][1]);
        acc1[1][0] = mfma16(w1, xa1[0][ks], acc1[1][0]);
        acc1[1][1] = mfma16(w1, xa1[1][ks], acc1[1][1]);
      }
      __builtin_amdgcn_s_setprio(0);
      const bool isq = (ch < 6);
      short* dst = isq ? qb : kb;
      const int h = isq ? ch : ch - 6;
      const float sc = isq ? QSC : 1.0f;
      size_t base0 = ((size_t)b0 * 6 + h) * 4096;
      size_t base1 = ((size_t)b1 * 6 + h) * 4096;
#pragma unroll
      for (int cf = 0; cf < 2; ++cf)
#pragma unroll
        for (int tf = 0; tf < 2; ++tf) {
          int tok = rowbase + tf * 16 + lr;
          int col = cf * 16 + r4;
          int idx = isq ? col : (col ^ (((tok >> 1) & 3) << 3));
          short4e s0, s1;
          s0[0] = f2bf(acc0[cf][tf][0] * sc);
          s0[1] = f2bf(acc0[cf][tf][1] * sc);
          s0[2] = f2bf(acc0[cf][tf][2] * sc);
          s0[3] = f2bf(acc0[cf][tf][3] * sc);
          s1[0] = f2bf(acc1[cf][tf][0] * sc);
          s1[1] = f2bf(acc1[cf][tf][1] * sc);
          s1[2] = f2bf(acc1[cf][tf][2] * sc);
          s1[3] = f2bf(acc1[cf][tf][3] * sc);
          *(short4e*)&dst[base0 + (size_t)tok * 32 + idx] = s0;
          *(short4e*)&dst[base1 + (size_t)tok * 32 + idx] = s1;
        }
    } else {
      // v: non-swapped MFMA, D[tok][wcol]; acc[tf][cf] -> v^T swizzled stores
      __builtin_amdgcn_s_setprio(1);
#pragma unroll
      for (int ks = 0; ks < 6; ++ks) {
        int cx = (ks * 64 + g * 16) ^ xorkey;
        short8 w0 = *(const short8*)(wb + lr * 384 + cx);
        short8 w1 = *(const short8*)(wb + (16 + lr) * 384 + cx);
        acc0[0][0] = mfma16(xa0[0][ks], w0, acc0[0][0]);
        acc0[0][1] = mfma16(xa0[0][ks], w1, acc0[0][1]);
        acc0[1][0] = mfma16(xa0[1][ks], w0, acc0[1][0]);
        acc0[1][1] = mfma16(xa0[1][ks], w1, acc0[1][1]);
        acc1[0][0] = mfma16(xa1[0][ks], w0, acc1[0][0]);
        acc1[0][1] = mfma16(xa1[0][ks], w1, acc1[0][1]);
        acc1[1][0] = mfma16(xa1[1][ks], w0, acc1[1][0]);
        acc1[1][1] = mfma16(xa1[1][ks], w1, acc1[1][1]);
      }
      __builtin_amdgcn_s_setprio(0);
      const int h = ch - 12;
      size_t base0 = ((size_t)b0 * 6 + h) * 4096;
      size_t base1 = ((size_t)b1 * 6 + h) * 4096;
#pragma unroll
      for (int tf = 0; tf < 2; ++tf)
#pragma unroll
        for (int cf = 0; cf < 2; ++cf) {
          int d = cf * 16 + lr;
          int rowpos = rowbase + tf * 16 + r4;
          int idx = rowpos ^ ((d & 15) << 3);
          short4e s0, s1;
          s0[0] = f2bf(acc0[tf][cf][0]);
          s0[1] = f2bf(acc0[tf][cf][1]);
          s0[2] = f2bf(acc0[tf][cf][2]);
          s0[3] = f2bf(acc0[tf][cf][3]);
          s1[0] = f2bf(acc1[tf][cf][0]);
          s1[1] = f2bf(acc1[tf][cf][1]);
          s1[2] = f2bf(acc1[tf][cf][2]);
          s1[3] = f2bf(acc1[tf][cf][3]);
          *(short4e*)&vb[base0 + (size_t)d * 128 + idx] = s0;
          *(short4e*)&vb[base1 + (size_t)d * 128 + idx] = s1;
        }
    }
    if (ch < 17) {
      // counted barrier: 8 stores (newest) stay in flight; 3 GLOADs drained.
      __builtin_amdgcn_sched_barrier(0);
      asm volatile("s_waitcnt vmcnt(8)" ::: "memory");
      __builtin_amdgcn_s_barrier();
      __builtin_amdgcn_sched_barrier(0);
    }
  }
}

// ---------------- attn per (window,head): GLOAD k/v, q direct, 32KB LDS, 4 blk/CU ----------------
__global__ __launch_bounds__(256, 4) void attn_kernel(const short* __restrict__ qb,
                                                      const short* __restrict__ kb,
                                                      const short* __restrict__ vb,
                                                      const float* __restrict__ bmF,
                                                      char* __restrict__ outc) {
  __shared__ char sbuf[16384];   // k 8KB | v 8KB (swizzled images)
  __shared__ short p_lds[8192];  // 4 waves x 4KB P scratch
  const int bh = blockIdx.x, b = bh / 6, h = bh - b * 6;
  const short* qt = qb + (size_t)bh * 4096;
  const char* kc = (const char*)(kb + (size_t)bh * 4096);
  const char* vc = (const char*)(vb + (size_t)bh * 4096);
  const float4* bm4 = (const float4*)(bmF + ((size_t)h * 64 + (b & 63)) * 16384);
  short* outSlot = (short*)(outc + (size_t)b * 98304 + 49152);
  const int tid = threadIdx.x, wave = tid >> 6, lane = tid & 63;
  const int lr = lane & 15, g = lane >> 4, r4 = g * 4;
  const int rowbase = wave * 32;
  const int wl = wave * 1024 + lane * 16;
  const int wu = wave * 1024;

  GLOAD16(kc + wl,        sbuf + wu);
  GLOAD16(kc + 4096 + wl, sbuf + 4096 + wu);
  GLOAD16(vc + wl,        sbuf + 8192 + wu);
  GLOAD16(vc + 4096 + wl, sbuf + 12288 + wu);
  short8 qaH[2];
  qaH[0] = *(const short8*)&qt[(rowbase + lr) * 32 + g * 8];
  qaH[1] = *(const short8*)&qt[(rowbase + 16 + lr) * 32 + g * 8];
  __syncthreads();

  const char* ksb = sbuf;
  const char* vs = sbuf + 8192;
  char* pw = (char*)p_lds + wave * 4096;
  const int kkey = ((lr >> 1) & 3) << 4;

#pragma unroll
  for (int rf = 0; rf < 2; ++rf) {
    float4 bmv[8];
#pragma unroll
    for (int i = 0; i < 8; ++i) bmv[i] = bm4[(rf * 8 + i) * 256 + tid];
    short8 qa = qaH[rf];
    f32x4 s[8];
    __builtin_amdgcn_s_setprio(1);
#pragma unroll
    for (int cf = 0; cf < 8; ++cf) {
      int krow = cf * 16 + lr;
      short8 kf = *(const short8*)(ksb + krow * 64 + ((g * 16) ^ kkey));
      f32x4 z = {0.f, 0.f, 0.f, 0.f};
      s[cf] = mfma16(qa, kf, z);
    }
    __builtin_amdgcn_s_setprio(0);
    float inv_[4];
#pragma unroll
    for (int rg = 0; rg < 4; ++rg) {
      float4 bb0 = bmv[rg * 2];
      float4 bb1 = bmv[rg * 2 + 1];
      float p0 = exp2f(s[0][rg] + bb0.x);
      float p1 = exp2f(s[1][rg] + bb0.y);
      float p2 = exp2f(s[2][rg] + bb0.z);
      float p3 = exp2f(s[3][rg] + bb0.w);
      float p4 = exp2f(s[4][rg] + bb1.x);
      float p5 = exp2f(s[5][rg] + bb1.y);
      float p6 = exp2f(s[6][rg] + bb1.z);
      float p7 = exp2f(s[7][rg] + bb1.w);
      float sum = ((p0 + p1) + (p2 + p3)) + ((p4 + p5) + (p6 + p7));
#pragma unroll
      for (int o = 1; o < 16; o <<= 1) sum += __shfl_xor(sum, o);
      inv_[rg] = 1.0f / sum;
      int rr = r4 + rg;
      int base = rr * 256 + (lr << 1);
      int swz = rr << 4;
      *(short*)(pw + ((base + 0 * 32) ^ swz)) = f2bf(p0);
      *(short*)(pw + ((base + 1 * 32) ^ swz)) = f2bf(p1);
      *(short*)(pw + ((base + 2 * 32) ^ swz)) = f2bf(p2);
      *(short*)(pw + ((base + 3 * 32) ^ swz)) = f2bf(p3);
      *(short*)(pw + ((base + 4 * 32) ^ swz)) = f2bf(p4);
      *(short*)(pw + ((base + 5 * 32) ^ swz)) = f2bf(p5);
      *(short*)(pw + ((base + 6 * 32) ^ swz)) = f2bf(p6);
      *(short*)(pw + ((base + 7 * 32) ^ swz)) = f2bf(p7);
    }
    f32x4 o0 = {0.f, 0.f, 0.f, 0.f}, o1 = {0.f, 0.f, 0.f, 0.f};
#pragma unroll
    for (int kst = 0; kst < 4; ++kst) {
      short8 pa = *(const short8*)(pw + ((lr * 256 + kst * 64 + g * 16) ^ (lr << 4)));
      short8 vb0 = *(const short8*)(vs + ((lr * 256 + kst * 64 + g * 16) ^ ((lr & 15) << 4)));
      short8 vb1 = *(const short8*)(vs + (((16 + lr) * 256 + kst * 64 + g * 16) ^ (((16 + lr) & 15) << 4)));
      __builtin_amdgcn_s_setprio(1);
      o0 = mfma16(pa, vb0, o0);
      o1 = mfma16(pa, vb1, o1);
      __builtin_amdgcn_s_setprio(0);
    }
#pragma unroll
    for (int rg = 0; rg < 4; ++rg) {
      int tok = rowbase + rf * 16 + r4 + rg;
      float iv = inv_[rg];
      outSlot[(size_t)tok * 192 + h * 32 + lr] = f2bf(o0[rg] * iv);
      outSlot[(size_t)tok * 192 + h * 32 + 16 + lr] = f2bf(o1[rg] * iv);
    }
  }
}

// ---------------- proj: ain[128][192] (bf16 in own d_out slot) @ proj_w^T + b ----------------
__global__ __launch_bounds__(256, 2) void proj_kernel(const short* __restrict__ pwbf,
                                                      const float* __restrict__ pb,
                                                      float* __restrict__ out) {
  __shared__ short at[24576];
  __shared__ short wt[2][6144];
  const int b = blockIdx.x, tid = threadIdx.x;
  const int wave = tid >> 6, lane = tid & 63;
  const int lr = lane & 15, g = lane >> 4;
  const int g16 = g * 16, r4 = g * 4;
  const int rowbase = wave * 32;
  const int xorkey = (lr & 7) << 4;
  char* atb = (char*)at;
  char* wtb = (char*)wt;

  int wsoff[3], wdoff[3];
#pragma unroll
  for (int i = 0; i < 3; ++i) {
    int idx8 = i * 256 + tid;
    int r = idx8 / 24, c = idx8 - r * 24;
    wsoff[i] = idx8 * 8;
    wdoff[i] = r * 384 + ((c * 16) ^ ((r & 7) << 4));
  }
  short8 wreg[3];
#pragma unroll
  for (int i = 0; i < 3; ++i) wreg[i] = *(const short8*)(pwbf + wsoff[i]);

  const short8* ar = (const short8*)((const char*)out + (size_t)b * 98304 + 49152);
#pragma unroll
  for (int i = 0; i < 12; ++i) {
    int idx8 = i * 256 + tid;
    int r = idx8 / 24, c = idx8 - r * 24;
    short8 v = ar[idx8];
    *(short8*)(atb + r * 384 + ((c * 16) ^ ((r & 7) << 4))) = v;
  }
#pragma unroll
  for (int i = 0; i < 3; ++i) *(short8*)(wtb + wdoff[i]) = wreg[i];
  __syncthreads();

  const int rA0 = (rowbase + lr) * 384, rA1 = rA0 + 16 * 384;
  const int wB0 = lr * 384, wB1 = wB0 + 16 * 384;

  for (int ch = 0; ch < 6; ++ch) {
    if (ch < 5) {
#pragma unroll
      for (int i = 0; i < 3; ++i)
        wreg[i] = *(const short8*)(pwbf + (ch + 1) * 6144 + wsoff[i]);
    }
    const char* wbuf = wtb + (ch & 1) * 12288;
    f32x4 acc[2][2];
    acc[0][0] = acc[0][1] = acc[1][0] = acc[1][1] = f32x4{0.f, 0.f, 0.f, 0.f};
#pragma unroll
    for (int ks = 0; ks < 6; ++ks) {
      int cx = (ks * 64 + g16) ^ xorkey;
      short8 xa0 = *(const short8*)(atb + rA0 + cx);
      short8 xa1 = *(const short8*)(atb + rA1 + cx);
      short8 wf0 = *(const short8*)(wbuf + wB0 + cx);
      short8 wf1 = *(const short8*)(wbuf + wB1 + cx);
      acc[0][0] = mfma16(xa0, wf0, acc[0][0]);
      acc[0][1] = mfma16(xa0, wf1, acc[0][1]);
      acc[1][0] = mfma16(xa1, wf0, acc[1][0]);
      acc[1][1] = mfma16(xa1, wf1, acc[1][1]);
    }
#pragma unroll
    for (int cf = 0; cf < 2; ++cf) {
      int j = ch * 32 + cf * 16 + lr;
      float bj = pb[j];
#pragma unroll
      for (int rf = 0; rf < 2; ++rf)
#pragma unroll
        for (int rg = 0; rg < 4; ++rg) {
          int tok = rowbase + rf * 16 + r4 + rg;
          out[((size_t)b * 128 + tok) * 192 + j] = acc[rf][cf][rg] + bj;
        }
    }
    if (ch < 5) {
#pragma unroll
      for (int i = 0; i < 3; ++i)
        *(short8*)(wtb + ((ch + 1) & 1) * 12288 + wdoff[i]) = wreg[i];
      __syncthreads();
    }
  }
}

extern "C" void kernel_launch(void* const* d_in, const int* in_sizes, int n_in,
                              void* d_out, int out_size, void* d_ws, size_t ws_size,
                              hipStream_t stream) {
  const float* x      = (const float*)d_in[0];
  const float* mask   = (const float*)d_in[1];
  const float* qkv_w  = (const float*)d_in[2];
  const float* proj_w = (const float*)d_in[3];
  const float* proj_b = (const float*)d_in[4];
  const float* table  = (const float*)d_in[5];
  const int*   rel    = (const int*)d_in[6];
  char* ws = (char*)d_ws;
  size_t o = 0;
  float* bmF  = (float*)(ws + o); o += 25165824;   // 384 * 16384 * 4
  short* wbf  = (short*)(ws + o); o += 221184;
  short* pwbf = (short*)(ws + o); o += 73728;
  short* qbp  = (short*)(ws + o); o += 50331648;
  short* kbp  = (short*)(ws + o); o += 50331648;
  short* vbp  = (short*)(ws + o); o += 50331648;
  float* out = (float*)d_out;

  prep_kernel<<<528, 256, 0, stream>>>(qkv_w, proj_w, rel, table, mask, wbf, pwbf, bmF);
  qkv_kernel<<<512, 256, 0, stream>>>(x, wbf, qbp, kbp, vbp);
  attn_kernel<<<6144, 256, 0, stream>>>(qbp, kbp, vbp, bmF, (char*)d_out);
  proj_kernel<<<1024, 256, 0, stream>>>(pwbf, proj_b, (float*)d_out);
}

// Round 19
// 168.608 us; speedup vs baseline: 1.3699x; 1.0164x over previous
//
#include <hip/hip_runtime.h>
#include <hip/hip_bf16.h>

// WindowAttention v19: r18 (171.4us proven) + XCD-aware attn block swizzle:
// blockIdx n -> tile = n%384 (h*64+w), rep = n/384, b = rep*64+w. All 16 blocks
// sharing a bm tile land on one XCD (384%8==0) -> bm L2-resident (3MB/XCD).
// N=128 tokens, B_=1024 windows, C=192, H=6, hd=32.
// ws: bmF f32 [6*64][16384] ((bias+mask)*LOG2E, r6 frag order) |
//     wbf bf16[576][192] GLOBAL-SWIZZLED (short col ^ (row&7)<<3) | pwbf linear |
//     q bf16 [b][h][128][32] linear, pre-scaled SCALE*LOG2E |
//     k swz (short col ^ ((tok>>1)&3)<<3) | v^T swz (short col ^ (d&15)<<3)
// attn bf16 out in d_out slot: d_out + b*98304 + 49152 (block-private).

typedef float f32x4 __attribute__((ext_vector_type(4)));
typedef short short8 __attribute__((ext_vector_type(8)));
typedef short short4e __attribute__((ext_vector_type(4)));

#define SCALE 0.17677669529663687f
#define LOG2E 1.4426950408889634f
#define QSC (SCALE * LOG2E)

#define GLOAD16(src, dst)                                                      \
  __builtin_amdgcn_global_load_lds(                                            \
      (const __attribute__((address_space(1))) unsigned int*)(const void*)(src),\
      (__attribute__((address_space(3))) unsigned int*)(void*)(dst), 16, 0, 0)

static __device__ __forceinline__ short f2bf(float f) {
  __hip_bfloat16 h = __float2bfloat16(f);
  return __builtin_bit_cast(short, h);
}
static __device__ __forceinline__ f32x4 mfma16(short8 a, short8 b, f32x4 c) {
  return __builtin_amdgcn_mfma_f32_16x16x32_bf16(a, b, c, 0, 0, 0);
}

// ---------------- prep (merged): W conversion + bm tiles ----------------
__global__ __launch_bounds__(256) void prep_kernel(const float* __restrict__ qkvw,
                                                   const float* __restrict__ projw,
                                                   const int* __restrict__ rel,
                                                   const float* __restrict__ table,
                                                   const float* __restrict__ mask,
                                                   short* __restrict__ wbf,
                                                   short* __restrict__ pwbf,
                                                   float* __restrict__ bmF) {
  int blk = blockIdx.x;
  if (blk < 144) {
    int t = blk * 256 + threadIdx.x;  // float4 index 0..36863
    const int NQ = 27648;             // 576*192/4
    float4 f; short* dst;
    if (t < NQ) {
      f = ((const float4*)qkvw)[t];
      int row = (t * 4) / 192, c4 = (t * 4) % 192;
      dst = wbf + row * 192 + (c4 ^ ((row & 7) << 3));  // row-local swizzle
    } else {
      f = ((const float4*)projw)[t - NQ];
      dst = pwbf + (t - NQ) * 4;
    }
    short4e o; o[0] = f2bf(f.x); o[1] = f2bf(f.y); o[2] = f2bf(f.z); o[3] = f2bf(f.w);
    *(short4e*)dst = o;
  } else {
    int bb = blk - 144;                 // 384 blocks: h*64 + w
    int h = bb >> 6, w = bb & 63;
    int tid = threadIdx.x, lane = tid & 63, wave = tid >> 6;
    int lr = lane & 15, r4 = (lane >> 4) * 4;
    const float* mk = mask + (size_t)w * 16384;
    float* dst = bmF + (size_t)bb * 16384;
#pragma unroll
    for (int L = 0; L < 16; ++L) {
      int rf = L >> 3, rg = (L >> 1) & 3, cp = L & 1;
      int row = wave * 32 + rf * 16 + r4 + rg;
      float4 v;
#pragma unroll
      for (int e = 0; e < 4; ++e) {
        int col = (cp * 4 + e) * 16 + lr;
        float bias = table[rel[row * 128 + col] * 6 + h];
        ((float*)&v)[e] = (bias + mk[row * 128 + col]) * LOG2E;
      }
      ((float4*)dst)[L * 256 + tid] = v;
    }
  }
}

// ---------------- qkv: 2 windows/block, counted-vmcnt(8) barriers ----------------
__global__ __launch_bounds__(256, 2) void qkv_kernel(const float* __restrict__ x,
                                                     const short* __restrict__ wbf,
                                                     short* __restrict__ qb,
                                                     short* __restrict__ kb,
                                                     short* __restrict__ vb) {
  __shared__ short wt[2][6144];  // [32][192] bf16 dbuf, image already swizzled
  char* wtb = (char*)wt;
  const int bid = blockIdx.x;
  const int b0 = bid * 2, b1 = bid * 2 + 1;
  const int tid = threadIdx.x;
  const int wave = tid >> 6, lane = tid & 63;
  const int lr = lane & 15, g = lane >> 4, g8 = g * 8, r4 = g * 4;
  const int rowbase = wave * 32;
  const int xorkey = (lr & 7) << 4;
  const int wl = wave * 1024 + lane * 16;   // per-lane src byte offset
  const int wu = wave * 1024;               // wave-uniform LDS byte offset

  // x -> fragments for BOTH windows
  short8 xa0[2][6], xa1[2][6];
  {
    const float* xr0 = x + (size_t)b0 * 24576 + (size_t)(rowbase + lr) * 192;
    const float* xr1 = x + (size_t)b1 * 24576 + (size_t)(rowbase + lr) * 192;
#pragma unroll
    for (int tf = 0; tf < 2; ++tf)
#pragma unroll
      for (int ks = 0; ks < 6; ++ks) {
        const float* p0 = xr0 + tf * 16 * 192 + ks * 32 + g8;
        const float* p1 = xr1 + tf * 16 * 192 + ks * 32 + g8;
        float4 a0 = *(const float4*)p0;
        float4 a1 = *(const float4*)(p0 + 4);
        float4 c0 = *(const float4*)p1;
        float4 c1 = *(const float4*)(p1 + 4);
        short8 v8;
        v8[0] = f2bf(a0.x); v8[1] = f2bf(a0.y); v8[2] = f2bf(a0.z); v8[3] = f2bf(a0.w);
        v8[4] = f2bf(a1.x); v8[5] = f2bf(a1.y); v8[6] = f2bf(a1.z); v8[7] = f2bf(a1.w);
        xa0[tf][ks] = v8;
        short8 w8;
        w8[0] = f2bf(c0.x); w8[1] = f2bf(c0.y); w8[2] = f2bf(c0.z); w8[3] = f2bf(c0.w);
        w8[4] = f2bf(c1.x); w8[5] = f2bf(c1.y); w8[6] = f2bf(c1.z); w8[7] = f2bf(c1.w);
        xa1[tf][ks] = w8;
      }
  }
  // stage chunk 0
  {
    const char* wsrc = (const char*)wbf;
#pragma unroll
    for (int i = 0; i < 3; ++i)
      GLOAD16(wsrc + i * 4096 + wl, wtb + i * 4096 + wu);
  }
  __syncthreads();

  for (int ch = 0; ch < 18; ++ch) {
    if (ch < 17) {
      const char* wsrc = (const char*)wbf + (ch + 1) * 12288;
      char* wdst = wtb + ((ch + 1) & 1) * 12288;
#pragma unroll
      for (int i = 0; i < 3; ++i)
        GLOAD16(wsrc + i * 4096 + wl, wdst + i * 4096 + wu);
    }
    __builtin_amdgcn_sched_barrier(0);  // pin GLOAD issue before compute/stores
    const char* wb = wtb + (ch & 1) * 12288;
    f32x4 acc0[2][2], acc1[2][2];
    acc0[0][0] = acc0[0][1] = acc0[1][0] = acc0[1][1] = f32x4{0.f, 0.f, 0.f, 0.f};
    acc1[0][0] = acc1[0][1] = acc1[1][0] = acc1[1][1] = f32x4{0.f, 0.f, 0.f, 0.f};
    if (ch < 12) {
      // q/k: swapped MFMA, D[wcol][tok]; acc[cf][tf]
      __builtin_amdgcn_s_setprio(1);
#pragma unroll
      for (int ks = 0; ks < 6; ++ks) {
        int cx = (ks * 64 + g * 16) ^ xorkey;
        short8 w0 = *(const short8*)(wb + lr * 384 + cx);
        short8 w1 = *(const short8*)(wb + (16 + lr) * 384 + cx);
        acc0[0][0] = mfma16(w0, xa0[0][ks], acc0[0][0]);
        acc0[0][1] = mfma16(w0, xa0[1][ks], acc0[0][1]);
        acc0[1][0] = mfma16(w1, xa0[0][ks], acc0[1][0]);
        acc0[1][1] = mfma16(w1, xa0[1][ks], acc0[1][1]);
        acc1[0][0] = mfma16(w0, xa1[0][ks], acc1[0][0]);
        acc1[0][1] = mfma16(w0, xa1[1][ks], acc1[0][1]);
        acc1[1][0] = mfma16(w1, xa1[0][ks], acc1[1][0]);
        acc1[1][1] = mfma16(w1, xa1[1][ks], acc1[1][1]);
      }
      __builtin_amdgcn_s_setprio(0);
      const bool isq = (ch < 6);
      short* dst = isq ? qb : kb;
      const int h = isq ? ch : ch - 6;
      const float sc = isq ? QSC : 1.0f;
      size_t base0 = ((size_t)b0 * 6 + h) * 4096;
      size_t base1 = ((size_t)b1 * 6 + h) * 4096;
#pragma unroll
      for (int cf = 0; cf < 2; ++cf)
#pragma unroll
        for (int tf = 0; tf < 2; ++tf) {
          int tok = rowbase + tf * 16 + lr;
          int col = cf * 16 + r4;
          int idx = isq ? col : (col ^ (((tok >> 1) & 3) << 3));
          short4e s0, s1;
          s0[0] = f2bf(acc0[cf][tf][0] * sc);
          s0[1] = f2bf(acc0[cf][tf][1] * sc);
          s0[2] = f2bf(acc0[cf][tf][2] * sc);
          s0[3] = f2bf(acc0[cf][tf][3] * sc);
          s1[0] = f2bf(acc1[cf][tf][0] * sc);
          s1[1] = f2bf(acc1[cf][tf][1] * sc);
          s1[2] = f2bf(acc1[cf][tf][2] * sc);
          s1[3] = f2bf(acc1[cf][tf][3] * sc);
          *(short4e*)&dst[base0 + (size_t)tok * 32 + idx] = s0;
          *(short4e*)&dst[base1 + (size_t)tok * 32 + idx] = s1;
        }
    } else {
      // v: non-swapped MFMA, D[tok][wcol]; acc[tf][cf] -> v^T swizzled stores
      __builtin_amdgcn_s_setprio(1);
#pragma unroll
      for (int ks = 0; ks < 6; ++ks) {
        int cx = (ks * 64 + g * 16) ^ xorkey;
        short8 w0 = *(const short8*)(wb + lr * 384 + cx);
        short8 w1 = *(const short8*)(wb + (16 + lr) * 384 + cx);
        acc0[0][0] = mfma16(xa0[0][ks], w0, acc0[0][0]);
        acc0[0][1] = mfma16(xa0[0][ks], w1, acc0[0][1]);
        acc0[1][0] = mfma16(xa0[1][ks], w0, acc0[1][0]);
        acc0[1][1] = mfma16(xa0[1][ks], w1, acc0[1][1]);
        acc1[0][0] = mfma16(xa1[0][ks], w0, acc1[0][0]);
        acc1[0][1] = mfma16(xa1[0][ks], w1, acc1[0][1]);
        acc1[1][0] = mfma16(xa1[1][ks], w0, acc1[1][0]);
        acc1[1][1] = mfma16(xa1[1][ks], w1, acc1[1][1]);
      }
      __builtin_amdgcn_s_setprio(0);
      const int h = ch - 12;
      size_t base0 = ((size_t)b0 * 6 + h) * 4096;
      size_t base1 = ((size_t)b1 * 6 + h) * 4096;
#pragma unroll
      for (int tf = 0; tf < 2; ++tf)
#pragma unroll
        for (int cf = 0; cf < 2; ++cf) {
          int d = cf * 16 + lr;
          int rowpos = rowbase + tf * 16 + r4;
          int idx = rowpos ^ ((d & 15) << 3);
          short4e s0, s1;
          s0[0] = f2bf(acc0[tf][cf][0]);
          s0[1] = f2bf(acc0[tf][cf][1]);
          s0[2] = f2bf(acc0[tf][cf][2]);
          s0[3] = f2bf(acc0[tf][cf][3]);
          s1[0] = f2bf(acc1[tf][cf][0]);
          s1[1] = f2bf(acc1[tf][cf][1]);
          s1[2] = f2bf(acc1[tf][cf][2]);
          s1[3] = f2bf(acc1[tf][cf][3]);
          *(short4e*)&vb[base0 + (size_t)d * 128 + idx] = s0;
          *(short4e*)&vb[base1 + (size_t)d * 128 + idx] = s1;
        }
    }
    if (ch < 17) {
      // counted barrier: 8 stores (newest) stay in flight; 3 GLOADs drained.
      __builtin_amdgcn_sched_barrier(0);
      asm volatile("s_waitcnt vmcnt(8)" ::: "memory");
      __builtin_amdgcn_s_barrier();
      __builtin_amdgcn_sched_barrier(0);
    }
  }
}

// ---------------- attn per (window,head): XCD-swizzled block mapping ----------------
__global__ __launch_bounds__(256, 4) void attn_kernel(const short* __restrict__ qb,
                                                      const short* __restrict__ kb,
                                                      const short* __restrict__ vb,
                                                      const float* __restrict__ bmF,
                                                      char* __restrict__ outc) {
  __shared__ char sbuf[16384];   // k 8KB | v 8KB (swizzled images)
  __shared__ short p_lds[8192];  // 4 waves x 4KB P scratch
  // XCD swizzle: n = rep*384 + tile; tile = h*64 + w; b = rep*64 + w.
  // All 16 reps of a tile are congruent mod 384 (and mod 8) -> same XCD -> bm L2-hot.
  const int n = blockIdx.x;
  const int tile = n % 384, rep = n / 384;
  const int h = tile >> 6, w = tile & 63;
  const int b = rep * 64 + w;
  const size_t bh = (size_t)b * 6 + h;
  const short* qt = qb + bh * 4096;
  const char* kc = (const char*)(kb + bh * 4096);
  const char* vc = (const char*)(vb + bh * 4096);
  const float4* bm4 = (const float4*)(bmF + (size_t)tile * 16384);
  short* outSlot = (short*)(outc + (size_t)b * 98304 + 49152);
  const int tid = threadIdx.x, wave = tid >> 6, lane = tid & 63;
  const int lr = lane & 15, g = lane >> 4, r4 = g * 4;
  const int rowbase = wave * 32;
  const int wl = wave * 1024 + lane * 16;
  const int wu = wave * 1024;

  GLOAD16(kc + wl,        sbuf + wu);
  GLOAD16(kc + 4096 + wl, sbuf + 4096 + wu);
  GLOAD16(vc + wl,        sbuf + 8192 + wu);
  GLOAD16(vc + 4096 + wl, sbuf + 12288 + wu);
  short8 qaH[2];
  qaH[0] = *(const short8*)&qt[(rowbase + lr) * 32 + g * 8];
  qaH[1] = *(const short8*)&qt[(rowbase + 16 + lr) * 32 + g * 8];
  __syncthreads();

  const char* ksb = sbuf;
  const char* vs = sbuf + 8192;
  char* pw = (char*)p_lds + wave * 4096;
  const int kkey = ((lr >> 1) & 3) << 4;

#pragma unroll
  for (int rf = 0; rf < 2; ++rf) {
    float4 bmv[8];
#pragma unroll
    for (int i = 0; i < 8; ++i) bmv[i] = bm4[(rf * 8 + i) * 256 + tid];
    short8 qa = qaH[rf];
    f32x4 s[8];
    __builtin_amdgcn_s_setprio(1);
#pragma unroll
    for (int cf = 0; cf < 8; ++cf) {
      int krow = cf * 16 + lr;
      short8 kf = *(const short8*)(ksb + krow * 64 + ((g * 16) ^ kkey));
      f32x4 z = {0.f, 0.f, 0.f, 0.f};
      s[cf] = mfma16(qa, kf, z);
    }
    __builtin_amdgcn_s_setprio(0);
    float inv_[4];
#pragma unroll
    for (int rg = 0; rg < 4; ++rg) {
      float4 bb0 = bmv[rg * 2];
      float4 bb1 = bmv[rg * 2 + 1];
      float p0 = exp2f(s[0][rg] + bb0.x);
      float p1 = exp2f(s[1][rg] + bb0.y);
      float p2 = exp2f(s[2][rg] + bb0.z);
      float p3 = exp2f(s[3][rg] + bb0.w);
      float p4 = exp2f(s[4][rg] + bb1.x);
      float p5 = exp2f(s[5][rg] + bb1.y);
      float p6 = exp2f(s[6][rg] + bb1.z);
      float p7 = exp2f(s[7][rg] + bb1.w);
      float sum = ((p0 + p1) + (p2 + p3)) + ((p4 + p5) + (p6 + p7));
#pragma unroll
      for (int o = 1; o < 16; o <<= 1) sum += __shfl_xor(sum, o);
      inv_[rg] = 1.0f / sum;
      int rr = r4 + rg;
      int base = rr * 256 + (lr << 1);
      int swz = rr << 4;
      *(short*)(pw + ((base + 0 * 32) ^ swz)) = f2bf(p0);
      *(short*)(pw + ((base + 1 * 32) ^ swz)) = f2bf(p1);
      *(short*)(pw + ((base + 2 * 32) ^ swz)) = f2bf(p2);
      *(short*)(pw + ((base + 3 * 32) ^ swz)) = f2bf(p3);
      *(short*)(pw + ((base + 4 * 32) ^ swz)) = f2bf(p4);
      *(short*)(pw + ((base + 5 * 32) ^ swz)) = f2bf(p5);
      *(short*)(pw + ((base + 6 * 32) ^ swz)) = f2bf(p6);
      *(short*)(pw + ((base + 7 * 32) ^ swz)) = f2bf(p7);
    }
    f32x4 o0 = {0.f, 0.f, 0.f, 0.f}, o1 = {0.f, 0.f, 0.f, 0.f};
#pragma unroll
    for (int kst = 0; kst < 4; ++kst) {
      short8 pa = *(const short8*)(pw + ((lr * 256 + kst * 64 + g * 16) ^ (lr << 4)));
      short8 vb0 = *(const short8*)(vs + ((lr * 256 + kst * 64 + g * 16) ^ ((lr & 15) << 4)));
      short8 vb1 = *(const short8*)(vs + (((16 + lr) * 256 + kst * 64 + g * 16) ^ (((16 + lr) & 15) << 4)));
      __builtin_amdgcn_s_setprio(1);
      o0 = mfma16(pa, vb0, o0);
      o1 = mfma16(pa, vb1, o1);
      __builtin_amdgcn_s_setprio(0);
    }
#pragma unroll
    for (int rg = 0; rg < 4; ++rg) {
      int tok = rowbase + rf * 16 + r4 + rg;
      float iv = inv_[rg];
      outSlot[(size_t)tok * 192 + h * 32 + lr] = f2bf(o0[rg] * iv);
      outSlot[(size_t)tok * 192 + h * 32 + 16 + lr] = f2bf(o1[rg] * iv);
    }
  }
}

// ---------------- proj: ain[128][192] (bf16 in own d_out slot) @ proj_w^T + b ----------------
__global__ __launch_bounds__(256, 2) void proj_kernel(const short* __restrict__ pwbf,
                                                      const float* __restrict__ pb,
                                                      float* __restrict__ out) {
  __shared__ short at[24576];
  __shared__ short wt[2][6144];
  const int b = blockIdx.x, tid = threadIdx.x;
  const int wave = tid >> 6, lane = tid & 63;
  const int lr = lane & 15, g = lane >> 4;
  const int g16 = g * 16, r4 = g * 4;
  const int rowbase = wave * 32;
  const int xorkey = (lr & 7) << 4;
  char* atb = (char*)at;
  char* wtb = (char*)wt;

  int wsoff[3], wdoff[3];
#pragma unroll
  for (int i = 0; i < 3; ++i) {
    int idx8 = i * 256 + tid;
    int r = idx8 / 24, c = idx8 - r * 24;
    wsoff[i] = idx8 * 8;
    wdoff[i] = r * 384 + ((c * 16) ^ ((r & 7) << 4));
  }
  short8 wreg[3];
#pragma unroll
  for (int i = 0; i < 3; ++i) wreg[i] = *(const short8*)(pwbf + wsoff[i]);

  const short8* ar = (const short8*)((const char*)out + (size_t)b * 98304 + 49152);
#pragma unroll
  for (int i = 0; i < 12; ++i) {
    int idx8 = i * 256 + tid;
    int r = idx8 / 24, c = idx8 - r * 24;
    short8 v = ar[idx8];
    *(short8*)(atb + r * 384 + ((c * 16) ^ ((r & 7) << 4))) = v;
  }
#pragma unroll
  for (int i = 0; i < 3; ++i) *(short8*)(wtb + wdoff[i]) = wreg[i];
  __syncthreads();

  const int rA0 = (rowbase + lr) * 384, rA1 = rA0 + 16 * 384;
  const int wB0 = lr * 384, wB1 = wB0 + 16 * 384;

  for (int ch = 0; ch < 6; ++ch) {
    if (ch < 5) {
#pragma unroll
      for (int i = 0; i < 3; ++i)
        wreg[i] = *(const short8*)(pwbf + (ch + 1) * 6144 + wsoff[i]);
    }
    const char* wbuf = wtb + (ch & 1) * 12288;
    f32x4 acc[2][2];
    acc[0][0] = acc[0][1] = acc[1][0] = acc[1][1] = f32x4{0.f, 0.f, 0.f, 0.f};
#pragma unroll
    for (int ks = 0; ks < 6; ++ks) {
      int cx = (ks * 64 + g16) ^ xorkey;
      short8 xa0 = *(const short8*)(atb + rA0 + cx);
      short8 xa1 = *(const short8*)(atb + rA1 + cx);
      short8 wf0 = *(const short8*)(wbuf + wB0 + cx);
      short8 wf1 = *(const short8*)(wbuf + wB1 + cx);
      acc[0][0] = mfma16(xa0, wf0, acc[0][0]);
      acc[0][1] = mfma16(xa0, wf1, acc[0][1]);
      acc[1][0] = mfma16(xa1, wf0, acc[1][0]);
      acc[1][1] = mfma16(xa1, wf1, acc[1][1]);
    }
#pragma unroll
    for (int cf = 0; cf < 2; ++cf) {
      int j = ch * 32 + cf * 16 + lr;
      float bj = pb[j];
#pragma unroll
      for (int rf = 0; rf < 2; ++rf)
#pragma unroll
        for (int rg = 0; rg < 4; ++rg) {
          int tok = rowbase + rf * 16 + r4 + rg;
          out[((size_t)b * 128 + tok) * 192 + j] = acc[rf][cf][rg] + bj;
        }
    }
    if (ch < 5) {
#pragma unroll
      for (int i = 0; i < 3; ++i)
        *(short8*)(wtb + ((ch + 1) & 1) * 12288 + wdoff[i]) = wreg[i];
      __syncthreads();
    }
  }
}

extern "C" void kernel_launch(void* const* d_in, const int* in_sizes, int n_in,
                              void* d_out, int out_size, void* d_ws, size_t ws_size,
                              hipStream_t stream) {
  const float* x      = (const float*)d_in[0];
  const float* mask   = (const float*)d_in[1];
  const float* qkv_w  = (const float*)d_in[2];
  const float* proj_w = (const float*)d_in[3];
  const float* proj_b = (const float*)d_in[4];
  const float* table  = (const float*)d_in[5];
  const int*   rel    = (const int*)d_in[6];
  char* ws = (char*)d_ws;
  size_t o = 0;
  float* bmF  = (float*)(ws + o); o += 25165824;   // 384 * 16384 * 4
  short* wbf  = (short*)(ws + o); o += 221184;
  short* pwbf = (short*)(ws + o); o += 73728;
  short* qbp  = (short*)(ws + o); o += 50331648;
  short* kbp  = (short*)(ws + o); o += 50331648;
  short* vbp  = (short*)(ws + o); o += 50331648;
  float* out = (float*)d_out;

  prep_kernel<<<528, 256, 0, stream>>>(qkv_w, proj_w, rel, table, mask, wbf, pwbf, bmF);
  qkv_kernel<<<512, 256, 0, stream>>>(x, wbf, qbp, kbp, vbp);
  attn_kernel<<<6144, 256, 0, stream>>>(qbp, kbp, vbp, bmF, (char*)d_out);
  proj_kernel<<<1024, 256, 0, stream>>>(pwbf, proj_b, (float*)d_out);
}

// Round 20
// 165.700 us; speedup vs baseline: 1.3940x; 1.0175x over previous
//
#include <hip/hip_runtime.h>
#include <hip/hip_bf16.h>

// WindowAttention v20: r19 (168.6us proven) + qkv VGPR fix: drop the min-waves
// launch-bounds arg (alloc ~112 VGPR so both windows' x-fragments stay resident,
// no per-chunk remat/spill) + keep-alive pins on xa. Rest identical to r19.
// N=128 tokens, B_=1024 windows, C=192, H=6, hd=32.
// ws: bmF f32 [6*64][16384] ((bias+mask)*LOG2E, r6 frag order) |
//     wbf bf16[576][192] GLOBAL-SWIZZLED (short col ^ (row&7)<<3) | pwbf linear |
//     q bf16 [b][h][128][32] linear, pre-scaled SCALE*LOG2E |
//     k swz (short col ^ ((tok>>1)&3)<<3) | v^T swz (short col ^ (d&15)<<3)
// attn bf16 out in d_out slot: d_out + b*98304 + 49152 (block-private).

typedef float f32x4 __attribute__((ext_vector_type(4)));
typedef short short8 __attribute__((ext_vector_type(8)));
typedef short short4e __attribute__((ext_vector_type(4)));

#define SCALE 0.17677669529663687f
#define LOG2E 1.4426950408889634f
#define QSC (SCALE * LOG2E)

#define GLOAD16(src, dst)                                                      \
  __builtin_amdgcn_global_load_lds(                                            \
      (const __attribute__((address_space(1))) unsigned int*)(const void*)(src),\
      (__attribute__((address_space(3))) unsigned int*)(void*)(dst), 16, 0, 0)

static __device__ __forceinline__ short f2bf(float f) {
  __hip_bfloat16 h = __float2bfloat16(f);
  return __builtin_bit_cast(short, h);
}
static __device__ __forceinline__ f32x4 mfma16(short8 a, short8 b, f32x4 c) {
  return __builtin_amdgcn_mfma_f32_16x16x32_bf16(a, b, c, 0, 0, 0);
}
static __device__ __forceinline__ void keep8(short8& v) {
  asm volatile("" : "+v"(v));  // pin value live in VGPRs (anti-remat)
}

// ---------------- prep (merged): W conversion + bm tiles ----------------
__global__ __launch_bounds__(256) void prep_kernel(const float* __restrict__ qkvw,
                                                   const float* __restrict__ projw,
                                                   const int* __restrict__ rel,
                                                   const float* __restrict__ table,
                                                   const float* __restrict__ mask,
                                                   short* __restrict__ wbf,
                                                   short* __restrict__ pwbf,
                                                   float* __restrict__ bmF) {
  int blk = blockIdx.x;
  if (blk < 144) {
    int t = blk * 256 + threadIdx.x;  // float4 index 0..36863
    const int NQ = 27648;             // 576*192/4
    float4 f; short* dst;
    if (t < NQ) {
      f = ((const float4*)qkvw)[t];
      int row = (t * 4) / 192, c4 = (t * 4) % 192;
      dst = wbf + row * 192 + (c4 ^ ((row & 7) << 3));  // row-local swizzle
    } else {
      f = ((const float4*)projw)[t - NQ];
      dst = pwbf + (t - NQ) * 4;
    }
    short4e o; o[0] = f2bf(f.x); o[1] = f2bf(f.y); o[2] = f2bf(f.z); o[3] = f2bf(f.w);
    *(short4e*)dst = o;
  } else {
    int bb = blk - 144;                 // 384 blocks: h*64 + w
    int h = bb >> 6, w = bb & 63;
    int tid = threadIdx.x, lane = tid & 63, wave = tid >> 6;
    int lr = lane & 15, r4 = (lane >> 4) * 4;
    const float* mk = mask + (size_t)w * 16384;
    float* dst = bmF + (size_t)bb * 16384;
#pragma unroll
    for (int L = 0; L < 16; ++L) {
      int rf = L >> 3, rg = (L >> 1) & 3, cp = L & 1;
      int row = wave * 32 + rf * 16 + r4 + rg;
      float4 v;
#pragma unroll
      for (int e = 0; e < 4; ++e) {
        int col = (cp * 4 + e) * 16 + lr;
        float bias = table[rel[row * 128 + col] * 6 + h];
        ((float*)&v)[e] = (bias + mk[row * 128 + col]) * LOG2E;
      }
      ((float4*)dst)[L * 256 + tid] = v;
    }
  }
}

// ---------------- qkv: 2 windows/block, xa pinned in VGPRs, vmcnt(8) barriers ----------------
__global__ __launch_bounds__(256) void qkv_kernel(const float* __restrict__ x,
                                                  const short* __restrict__ wbf,
                                                  short* __restrict__ qb,
                                                  short* __restrict__ kb,
                                                  short* __restrict__ vb) {
  __shared__ short wt[2][6144];  // [32][192] bf16 dbuf, image already swizzled
  char* wtb = (char*)wt;
  const int bid = blockIdx.x;
  const int b0 = bid * 2, b1 = bid * 2 + 1;
  const int tid = threadIdx.x;
  const int wave = tid >> 6, lane = tid & 63;
  const int lr = lane & 15, g = lane >> 4, g8 = g * 8, r4 = g * 4;
  const int rowbase = wave * 32;
  const int xorkey = (lr & 7) << 4;
  const int wl = wave * 1024 + lane * 16;   // per-lane src byte offset
  const int wu = wave * 1024;               // wave-uniform LDS byte offset

  // x -> fragments for BOTH windows
  short8 xa0[2][6], xa1[2][6];
  {
    const float* xr0 = x + (size_t)b0 * 24576 + (size_t)(rowbase + lr) * 192;
    const float* xr1 = x + (size_t)b1 * 24576 + (size_t)(rowbase + lr) * 192;
#pragma unroll
    for (int tf = 0; tf < 2; ++tf)
#pragma unroll
      for (int ks = 0; ks < 6; ++ks) {
        const float* p0 = xr0 + tf * 16 * 192 + ks * 32 + g8;
        const float* p1 = xr1 + tf * 16 * 192 + ks * 32 + g8;
        float4 a0 = *(const float4*)p0;
        float4 a1 = *(const float4*)(p0 + 4);
        float4 c0 = *(const float4*)p1;
        float4 c1 = *(const float4*)(p1 + 4);
        short8 v8;
        v8[0] = f2bf(a0.x); v8[1] = f2bf(a0.y); v8[2] = f2bf(a0.z); v8[3] = f2bf(a0.w);
        v8[4] = f2bf(a1.x); v8[5] = f2bf(a1.y); v8[6] = f2bf(a1.z); v8[7] = f2bf(a1.w);
        xa0[tf][ks] = v8;
        short8 w8;
        w8[0] = f2bf(c0.x); w8[1] = f2bf(c0.y); w8[2] = f2bf(c0.z); w8[3] = f2bf(c0.w);
        w8[4] = f2bf(c1.x); w8[5] = f2bf(c1.y); w8[6] = f2bf(c1.z); w8[7] = f2bf(c1.w);
        xa1[tf][ks] = w8;
      }
  }
  // pin all fragments live (prevents per-chunk remat/spill)
#pragma unroll
  for (int tf = 0; tf < 2; ++tf)
#pragma unroll
    for (int ks = 0; ks < 6; ++ks) { keep8(xa0[tf][ks]); keep8(xa1[tf][ks]); }

  // stage chunk 0
  {
    const char* wsrc = (const char*)wbf;
#pragma unroll
    for (int i = 0; i < 3; ++i)
      GLOAD16(wsrc + i * 4096 + wl, wtb + i * 4096 + wu);
  }
  __syncthreads();

  for (int ch = 0; ch < 18; ++ch) {
    if (ch < 17) {
      const char* wsrc = (const char*)wbf + (ch + 1) * 12288;
      char* wdst = wtb + ((ch + 1) & 1) * 12288;
#pragma unroll
      for (int i = 0; i < 3; ++i)
        GLOAD16(wsrc + i * 4096 + wl, wdst + i * 4096 + wu);
    }
    __builtin_amdgcn_sched_barrier(0);  // pin GLOAD issue before compute/stores
    const char* wb = wtb + (ch & 1) * 12288;
    f32x4 acc0[2][2], acc1[2][2];
    acc0[0][0] = acc0[0][1] = acc0[1][0] = acc0[1][1] = f32x4{0.f, 0.f, 0.f, 0.f};
    acc1[0][0] = acc1[0][1] = acc1[1][0] = acc1[1][1] = f32x4{0.f, 0.f, 0.f, 0.f};
    if (ch < 12) {
      // q/k: swapped MFMA, D[wcol][tok]; acc[cf][tf]
      __builtin_amdgcn_s_setprio(1);
#pragma unroll
      for (int ks = 0; ks < 6; ++ks) {
        int cx = (ks * 64 + g * 16) ^ xorkey;
        short8 w0 = *(const short8*)(wb + lr * 384 + cx);
        short8 w1 = *(const short8*)(wb + (16 + lr) * 384 + cx);
        acc0[0][0] = mfma16(w0, xa0[0][ks], acc0[0][0]);
        acc0[0][1] = mfma16(w0, xa0[1][ks], acc0[0][1]);
        acc0[1][0] = mfma16(w1, xa0[0][ks], acc0[1][0]);
        acc0[1][1] = mfma16(w1, xa0[1][ks], acc0[1][1]);
        acc1[0][0] = mfma16(w0, xa1[0][ks], acc1[0][0]);
        acc1[0][1] = mfma16(w0, xa1[1][ks], acc1[0][1]);
        acc1[1][0] = mfma16(w1, xa1[0][ks], acc1[1][0]);
        acc1[1][1] = mfma16(w1, xa1[1][ks], acc1[1][1]);
      }
      __builtin_amdgcn_s_setprio(0);
      const bool isq = (ch < 6);
      short* dst = isq ? qb : kb;
      const int h = isq ? ch : ch - 6;
      const float sc = isq ? QSC : 1.0f;
      size_t base0 = ((size_t)b0 * 6 + h) * 4096;
      size_t base1 = ((size_t)b1 * 6 + h) * 4096;
#pragma unroll
      for (int cf = 0; cf < 2; ++cf)
#pragma unroll
        for (int tf = 0; tf < 2; ++tf) {
          int tok = rowbase + tf * 16 + lr;
          int col = cf * 16 + r4;
          int idx = isq ? col : (col ^ (((tok >> 1) & 3) << 3));
          short4e s0, s1;
          s0[0] = f2bf(acc0[cf][tf][0] * sc);
          s0[1] = f2bf(acc0[cf][tf][1] * sc);
          s0[2] = f2bf(acc0[cf][tf][2] * sc);
          s0[3] = f2bf(acc0[cf][tf][3] * sc);
          s1[0] = f2bf(acc1[cf][tf][0] * sc);
          s1[1] = f2bf(acc1[cf][tf][1] * sc);
          s1[2] = f2bf(acc1[cf][tf][2] * sc);
          s1[3] = f2bf(acc1[cf][tf][3] * sc);
          *(short4e*)&dst[base0 + (size_t)tok * 32 + idx] = s0;
          *(short4e*)&dst[base1 + (size_t)tok * 32 + idx] = s1;
        }
    } else {
      // v: non-swapped MFMA, D[tok][wcol]; acc[tf][cf] -> v^T swizzled stores
      __builtin_amdgcn_s_setprio(1);
#pragma unroll
      for (int ks = 0; ks < 6; ++ks) {
        int cx = (ks * 64 + g * 16) ^ xorkey;
        short8 w0 = *(const short8*)(wb + lr * 384 + cx);
        short8 w1 = *(const short8*)(wb + (16 + lr) * 384 + cx);
        acc0[0][0] = mfma16(xa0[0][ks], w0, acc0[0][0]);
        acc0[0][1] = mfma16(xa0[0][ks], w1, acc0[0][1]);
        acc0[1][0] = mfma16(xa0[1][ks], w0, acc0[1][0]);
        acc0[1][1] = mfma16(xa0[1][ks], w1, acc0[1][1]);
        acc1[0][0] = mfma16(xa1[0][ks], w0, acc1[0][0]);
        acc1[0][1] = mfma16(xa1[0][ks], w1, acc1[0][1]);
        acc1[1][0] = mfma16(xa1[1][ks], w0, acc1[1][0]);
        acc1[1][1] = mfma16(xa1[1][ks], w1, acc1[1][1]);
      }
      __builtin_amdgcn_s_setprio(0);
      const int h = ch - 12;
      size_t base0 = ((size_t)b0 * 6 + h) * 4096;
      size_t base1 = ((size_t)b1 * 6 + h) * 4096;
#pragma unroll
      for (int tf = 0; tf < 2; ++tf)
#pragma unroll
        for (int cf = 0; cf < 2; ++cf) {
          int d = cf * 16 + lr;
          int rowpos = rowbase + tf * 16 + r4;
          int idx = rowpos ^ ((d & 15) << 3);
          short4e s0, s1;
          s0[0] = f2bf(acc0[tf][cf][0]);
          s0[1] = f2bf(acc0[tf][cf][1]);
          s0[2] = f2bf(acc0[tf][cf][2]);
          s0[3] = f2bf(acc0[tf][cf][3]);
          s1[0] = f2bf(acc1[tf][cf][0]);
          s1[1] = f2bf(acc1[tf][cf][1]);
          s1[2] = f2bf(acc1[tf][cf][2]);
          s1[3] = f2bf(acc1[tf][cf][3]);
          *(short4e*)&vb[base0 + (size_t)d * 128 + idx] = s0;
          *(short4e*)&vb[base1 + (size_t)d * 128 + idx] = s1;
        }
    }
    if (ch < 17) {
      // counted barrier: 8 stores (newest) stay in flight; 3 GLOADs drained.
      __builtin_amdgcn_sched_barrier(0);
      asm volatile("s_waitcnt vmcnt(8)" ::: "memory");
      __builtin_amdgcn_s_barrier();
      __builtin_amdgcn_sched_barrier(0);
    }
  }
}

// ---------------- attn per (window,head): XCD-swizzled block mapping ----------------
__global__ __launch_bounds__(256, 4) void attn_kernel(const short* __restrict__ qb,
                                                      const short* __restrict__ kb,
                                                      const short* __restrict__ vb,
                                                      const float* __restrict__ bmF,
                                                      char* __restrict__ outc) {
  __shared__ char sbuf[16384];   // k 8KB | v 8KB (swizzled images)
  __shared__ short p_lds[8192];  // 4 waves x 4KB P scratch
  // XCD swizzle: n = rep*384 + tile; tile = h*64 + w; b = rep*64 + w.
  const int n = blockIdx.x;
  const int tile = n % 384, rep = n / 384;
  const int h = tile >> 6, w = tile & 63;
  const int b = rep * 64 + w;
  const size_t bh = (size_t)b * 6 + h;
  const short* qt = qb + bh * 4096;
  const char* kc = (const char*)(kb + bh * 4096);
  const char* vc = (const char*)(vb + bh * 4096);
  const float4* bm4 = (const float4*)(bmF + (size_t)tile * 16384);
  short* outSlot = (short*)(outc + (size_t)b * 98304 + 49152);
  const int tid = threadIdx.x, wave = tid >> 6, lane = tid & 63;
  const int lr = lane & 15, g = lane >> 4, r4 = g * 4;
  const int rowbase = wave * 32;
  const int wl = wave * 1024 + lane * 16;
  const int wu = wave * 1024;

  GLOAD16(kc + wl,        sbuf + wu);
  GLOAD16(kc + 4096 + wl, sbuf + 4096 + wu);
  GLOAD16(vc + wl,        sbuf + 8192 + wu);
  GLOAD16(vc + 4096 + wl, sbuf + 12288 + wu);
  short8 qaH[2];
  qaH[0] = *(const short8*)&qt[(rowbase + lr) * 32 + g * 8];
  qaH[1] = *(const short8*)&qt[(rowbase + 16 + lr) * 32 + g * 8];
  __syncthreads();

  const char* ksb = sbuf;
  const char* vs = sbuf + 8192;
  char* pw = (char*)p_lds + wave * 4096;
  const int kkey = ((lr >> 1) & 3) << 4;

#pragma unroll
  for (int rf = 0; rf < 2; ++rf) {
    float4 bmv[8];
#pragma unroll
    for (int i = 0; i < 8; ++i) bmv[i] = bm4[(rf * 8 + i) * 256 + tid];
    short8 qa = qaH[rf];
    f32x4 s[8];
    __builtin_amdgcn_s_setprio(1);
#pragma unroll
    for (int cf = 0; cf < 8; ++cf) {
      int krow = cf * 16 + lr;
      short8 kf = *(const short8*)(ksb + krow * 64 + ((g * 16) ^ kkey));
      f32x4 z = {0.f, 0.f, 0.f, 0.f};
      s[cf] = mfma16(qa, kf, z);
    }
    __builtin_amdgcn_s_setprio(0);
    float inv_[4];
#pragma unroll
    for (int rg = 0; rg < 4; ++rg) {
      float4 bb0 = bmv[rg * 2];
      float4 bb1 = bmv[rg * 2 + 1];
      float p0 = exp2f(s[0][rg] + bb0.x);
      float p1 = exp2f(s[1][rg] + bb0.y);
      float p2 = exp2f(s[2][rg] + bb0.z);
      float p3 = exp2f(s[3][rg] + bb0.w);
      float p4 = exp2f(s[4][rg] + bb1.x);
      float p5 = exp2f(s[5][rg] + bb1.y);
      float p6 = exp2f(s[6][rg] + bb1.z);
      float p7 = exp2f(s[7][rg] + bb1.w);
      float sum = ((p0 + p1) + (p2 + p3)) + ((p4 + p5) + (p6 + p7));
#pragma unroll
      for (int o = 1; o < 16; o <<= 1) sum += __shfl_xor(sum, o);
      inv_[rg] = 1.0f / sum;
      int rr = r4 + rg;
      int base = rr * 256 + (lr << 1);
      int swz = rr << 4;
      *(short*)(pw + ((base + 0 * 32) ^ swz)) = f2bf(p0);
      *(short*)(pw + ((base + 1 * 32) ^ swz)) = f2bf(p1);
      *(short*)(pw + ((base + 2 * 32) ^ swz)) = f2bf(p2);
      *(short*)(pw + ((base + 3 * 32) ^ swz)) = f2bf(p3);
      *(short*)(pw + ((base + 4 * 32) ^ swz)) = f2bf(p4);
      *(short*)(pw + ((base + 5 * 32) ^ swz)) = f2bf(p5);
      *(short*)(pw + ((base + 6 * 32) ^ swz)) = f2bf(p6);
      *(short*)(pw + ((base + 7 * 32) ^ swz)) = f2bf(p7);
    }
    f32x4 o0 = {0.f, 0.f, 0.f, 0.f}, o1 = {0.f, 0.f, 0.f, 0.f};
#pragma unroll
    for (int kst = 0; kst < 4; ++kst) {
      short8 pa = *(const short8*)(pw + ((lr * 256 + kst * 64 + g * 16) ^ (lr << 4)));
      short8 vb0 = *(const short8*)(vs + ((lr * 256 + kst * 64 + g * 16) ^ ((lr & 15) << 4)));
      short8 vb1 = *(const short8*)(vs + (((16 + lr) * 256 + kst * 64 + g * 16) ^ (((16 + lr) & 15) << 4)));
      __builtin_amdgcn_s_setprio(1);
      o0 = mfma16(pa, vb0, o0);
      o1 = mfma16(pa, vb1, o1);
      __builtin_amdgcn_s_setprio(0);
    }
#pragma unroll
    for (int rg = 0; rg < 4; ++rg) {
      int tok = rowbase + rf * 16 + r4 + rg;
      float iv = inv_[rg];
      outSlot[(size_t)tok * 192 + h * 32 + lr] = f2bf(o0[rg] * iv);
      outSlot[(size_t)tok * 192 + h * 32 + 16 + lr] = f2bf(o1[rg] * iv);
    }
  }
}

// ---------------- proj: ain[128][192] (bf16 in own d_out slot) @ proj_w^T + b ----------------
__global__ __launch_bounds__(256, 2) void proj_kernel(const short* __restrict__ pwbf,
                                                      const float* __restrict__ pb,
                                                      float* __restrict__ out) {
  __shared__ short at[24576];
  __shared__ short wt[2][6144];
  const int b = blockIdx.x, tid = threadIdx.x;
  const int wave = tid >> 6, lane = tid & 63;
  const int lr = lane & 15, g = lane >> 4;
  const int g16 = g * 16, r4 = g * 4;
  const int rowbase = wave * 32;
  const int xorkey = (lr & 7) << 4;
  char* atb = (char*)at;
  char* wtb = (char*)wt;

  int wsoff[3], wdoff[3];
#pragma unroll
  for (int i = 0; i < 3; ++i) {
    int idx8 = i * 256 + tid;
    int r = idx8 / 24, c = idx8 - r * 24;
    wsoff[i] = idx8 * 8;
    wdoff[i] = r * 384 + ((c * 16) ^ ((r & 7) << 4));
  }
  short8 wreg[3];
#pragma unroll
  for (int i = 0; i < 3; ++i) wreg[i] = *(const short8*)(pwbf + wsoff[i]);

  const short8* ar = (const short8*)((const char*)out + (size_t)b * 98304 + 49152);
#pragma unroll
  for (int i = 0; i < 12; ++i) {
    int idx8 = i * 256 + tid;
    int r = idx8 / 24, c = idx8 - r * 24;
    short8 v = ar[idx8];
    *(short8*)(atb + r * 384 + ((c * 16) ^ ((r & 7) << 4))) = v;
  }
#pragma unroll
  for (int i = 0; i < 3; ++i) *(short8*)(wtb + wdoff[i]) = wreg[i];
  __syncthreads();

  const int rA0 = (rowbase + lr) * 384, rA1 = rA0 + 16 * 384;
  const int wB0 = lr * 384, wB1 = wB0 + 16 * 384;

  for (int ch = 0; ch < 6; ++ch) {
    if (ch < 5) {
#pragma unroll
      for (int i = 0; i < 3; ++i)
        wreg[i] = *(const short8*)(pwbf + (ch + 1) * 6144 + wsoff[i]);
    }
    const char* wbuf = wtb + (ch & 1) * 12288;
    f32x4 acc[2][2];
    acc[0][0] = acc[0][1] = acc[1][0] = acc[1][1] = f32x4{0.f, 0.f, 0.f, 0.f};
#pragma unroll
    for (int ks = 0; ks < 6; ++ks) {
      int cx = (ks * 64 + g16) ^ xorkey;
      short8 xa0 = *(const short8*)(atb + rA0 + cx);
      short8 xa1 = *(const short8*)(atb + rA1 + cx);
      short8 wf0 = *(const short8*)(wbuf + wB0 + cx);
      short8 wf1 = *(const short8*)(wbuf + wB1 + cx);
      acc[0][0] = mfma16(xa0, wf0, acc[0][0]);
      acc[0][1] = mfma16(xa0, wf1, acc[0][1]);
      acc[1][0] = mfma16(xa1, wf0, acc[1][0]);
      acc[1][1] = mfma16(xa1, wf1, acc[1][1]);
    }
#pragma unroll
    for (int cf = 0; cf < 2; ++cf) {
      int j = ch * 32 + cf * 16 + lr;
      float bj = pb[j];
#pragma unroll
      for (int rf = 0; rf < 2; ++rf)
#pragma unroll
        for (int rg = 0; rg < 4; ++rg) {
          int tok = rowbase + rf * 16 + r4 + rg;
          out[((size_t)b * 128 + tok) * 192 + j] = acc[rf][cf][rg] + bj;
        }
    }
    if (ch < 5) {
#pragma unroll
      for (int i = 0; i < 3; ++i)
        *(short8*)(wtb + ((ch + 1) & 1) * 12288 + wdoff[i]) = wreg[i];
      __syncthreads();
    }
  }
}

extern "C" void kernel_launch(void* const* d_in, const int* in_sizes, int n_in,
                              void* d_out, int out_size, void* d_ws, size_t ws_size,
                              hipStream_t stream) {
  const float* x      = (const float*)d_in[0];
  const float* mask   = (const float*)d_in[1];
  const float* qkv_w  = (const float*)d_in[2];
  const float* proj_w = (const float*)d_in[3];
  const float* proj_b = (const float*)d_in[4];
  const float* table  = (const float*)d_in[5];
  const int*   rel    = (const int*)d_in[6];
  char* ws = (char*)d_ws;
  size_t o = 0;
  float* bmF  = (float*)(ws + o); o += 25165824;   // 384 * 16384 * 4
  short* wbf  = (short*)(ws + o); o += 221184;
  short* pwbf = (short*)(ws + o); o += 73728;
  short* qbp  = (short*)(ws + o); o += 50331648;
  short* kbp  = (short*)(ws + o); o += 50331648;
  short* vbp  = (short*)(ws + o); o += 50331648;
  float* out = (float*)d_out;

  prep_kernel<<<528, 256, 0, stream>>>(qkv_w, proj_w, rel, table, mask, wbf, pwbf, bmF);
  qkv_kernel<<<512, 256, 0, stream>>>(x, wbf, qbp, kbp, vbp);
  attn_kernel<<<6144, 256, 0, stream>>>(qbp, kbp, vbp, bmF, (char*)d_out);
  proj_kernel<<<1024, 256, 0, stream>>>(pwbf, proj_b, (float*)d_out);
}